// Round 4
// baseline (493.300 us; speedup 1.0000x reference)
//
#include <hip/hip_runtime.h>
#include <hip/hip_bf16.h>
#include <cstdint>
#include <cstddef>

// ---------------------------------------------------------------------------
// MaskedSelfAttention: B=2, T=2048, C=2048, NH=16, NG=4, D=128
// sliding window 512 + sink 4, RoPE base 10000, pos 0.
// fp32 I/O; bf16 MFMA internally (fp32 accum).
// Workspace (32 MB):
//   [0,16M):  xb [4096][2048] bf16 -> later At [2][2048][2048] bf16
//   [16,28M): Wqkvt [3072][2048] bf16 -> later Wot [2048][2048] (16-24M)
// d_out scratch (33.5 MB fp32, dead until final O-GEMM):
//   [0,16.78M): Qb [4096][2048] bf16
//   [16.78,20.97M): Kb [4096][512] bf16
//   [20.97,25.17M): Vt [512][4096] bf16
// ---------------------------------------------------------------------------

typedef short s16;
typedef short short8 __attribute__((ext_vector_type(8)));
typedef short s16x4  __attribute__((ext_vector_type(4)));
typedef float f32x4  __attribute__((ext_vector_type(4)));

#define MFMA16(a, b, c) __builtin_amdgcn_mfma_f32_16x16x32_bf16((a), (b), (c), 0, 0, 0)

__device__ __forceinline__ float bf2f(s16 u) {
    union { float f; uint32_t i; } v;
    v.i = ((uint32_t)(uint16_t)u) << 16;
    return v.f;
}
__device__ __forceinline__ s16 f2bf(float f) {
    union { float f; uint32_t i; } v;
    v.f = f;
    uint32_t r = v.i + 0x7FFFu + ((v.i >> 16) & 1u);   // RNE
    return (s16)(r >> 16);
}

// async global->LDS, 16 B per lane; LDS dest = wave-uniform base + lane*16
__device__ __forceinline__ void gload16(const s16* g, s16* l) {
    __builtin_amdgcn_global_load_lds(
        (const __attribute__((address_space(1))) void*)g,
        (__attribute__((address_space(3))) void*)l, 16, 0, 0);
}

// ---------------------------------------------------------------------------
// Elementwise fp32 -> bf16 cast (8 elems/thread).
// ---------------------------------------------------------------------------
__global__ __launch_bounds__(256)
void cast_bf16(const float* __restrict__ in, s16* __restrict__ out)
{
    size_t i = ((size_t)blockIdx.x * 256 + threadIdx.x) * 8;
    f32x4 f0 = *(const f32x4*)(in + i);
    f32x4 f1 = *(const f32x4*)(in + i + 4);
    short8 h;
    h[0]=f2bf(f0[0]); h[1]=f2bf(f0[1]); h[2]=f2bf(f0[2]); h[3]=f2bf(f0[3]);
    h[4]=f2bf(f1[0]); h[5]=f2bf(f1[1]); h[6]=f2bf(f1[2]); h[7]=f2bf(f1[3]);
    *(short8*)(out + i) = h;
}

// ---------------------------------------------------------------------------
// Transpose+cast all three QKV weights into Wqkvt [3072][2048]:
//   rows 0-2047 = Wq^T, 2048-2559 = Wk^T, 2560-3071 = Wv^T. K=2048 fixed.
// ---------------------------------------------------------------------------
__global__ __launch_bounds__(256)
void castT3(const float* __restrict__ Wq, const float* __restrict__ Wk,
            const float* __restrict__ Wv, s16* __restrict__ out)
{
    int z = blockIdx.z;
    const float* in; s16* dst; int N;
    if (z == 0)      { in = Wq; dst = out;                        N = 2048; }
    else if (z == 1) { in = Wk; dst = out + (size_t)2048 * 2048;  N = 512; }
    else             { in = Wv; dst = out + (size_t)2560 * 2048;  N = 512; }
    int n0 = blockIdx.x * 32, k0 = blockIdx.y * 32;
    if (n0 >= N) return;

    __shared__ float t[32][33];
    int tx = threadIdx.x & 31, ty = threadIdx.x >> 5;
    for (int i = 0; i < 32; i += 8)
        t[ty + i][tx] = in[(size_t)(k0 + ty + i) * N + n0 + tx];
    __syncthreads();
    for (int i = 0; i < 32; i += 8)
        dst[(size_t)(n0 + ty + i) * 2048 + k0 + tx] = f2bf(t[tx][ty + i]);
}

// ---------------------------------------------------------------------------
// Single-weight transpose+cast: fp32 [2048][2048] -> bf16 [2048][2048]^T.
// ---------------------------------------------------------------------------
__global__ __launch_bounds__(256)
void castT(const float* __restrict__ in, s16* __restrict__ out)
{
    __shared__ float t[32][33];
    int n0 = blockIdx.x * 32, k0 = blockIdx.y * 32;
    int tx = threadIdx.x & 31, ty = threadIdx.x >> 5;
    for (int i = 0; i < 32; i += 8)
        t[ty + i][tx] = in[(size_t)(k0 + ty + i) * 2048 + n0 + tx];
    __syncthreads();
    for (int i = 0; i < 32; i += 8)
        out[(size_t)(n0 + ty + i) * 2048 + k0 + tx] = f2bf(t[tx][ty + i]);
}

// ---------------------------------------------------------------------------
// GEMM v4b: out = A[M][K] x Bt[N][K]^T + bias.  256x256 tile, BK=64, 512 thr
// = 8 waves (2M x 4N), per-wave C = 128x64 (acc[8][4] of 16x16 frags).
// Deep pipeline (T2+T3/T4+T5 from learn_hip m198/m201):
//  - LDS 128 KB: A,B double-buffered [256][64] bf16, XOR-swizzled:
//    global (row, k-chunk kc) lives at LDS byte row*128 + ((kc^(row&7))<<4).
//    global_load_lds writes linearly; swizzle applied by pre-swizzling the
//    per-lane GLOBAL source column (rule #21).
//  - READ side (v4 bugfix): chunk byte offset is (fq*16 + k2*64) XOR
//    ((fr&7)<<4) -- must be XOR across bits 4-6, NOT kx + k2*64 (the add
//    carries into the row bits when fr&7 >= 4; that was v4's absmax=205).
//    kx0 = (fq^(fr&7))<<4, kx1 = kx0^64, select per k2.
//  - per K-tile, 4 phases: {ds_read subtile | stage 1/4 of tile t+1
//    (2x gload16) | s_barrier | lgkmcnt(0) | setprio(1) 16 MFMA setprio(0)}.
//    vmcnt(0) drain only once per tile, AFTER the last MFMA cluster.
// MODE 0: QKV split epilogue (n<2048 -> Qb bf16; n<2560 -> Kb bf16;
//         else Vt bf16 transposed).  MODE 2: fp32 out + bias.
// mfma_f32_16x16x32_bf16 layouts (verified m89/m91):
//   A-frag: A[m=lane&15][k=(lane>>4)*8+j]; B-frag: B[k=(lane>>4)*8+j][n=lane&15]
//   C/D:    row=(lane>>4)*4+reg, col=lane&15
// ---------------------------------------------------------------------------
template <int MODE>
__global__ __launch_bounds__(512, 2)
void gemm256(const s16* __restrict__ A, const s16* __restrict__ Bt,
             const float* __restrict__ b0, const float* __restrict__ b1,
             const float* __restrict__ b2,
             void* __restrict__ o0, void* __restrict__ o1, void* __restrict__ o2,
             int M, int N, int K)
{
    __shared__ s16 As[2][16384];   // [buf][256 rows x 64 cols], 32 KB each
    __shared__ s16 Bs[2][16384];

    const int tid  = threadIdx.x;
    const int lane = tid & 63, wv = tid >> 6;
    const int m0 = blockIdx.x * 256, n0 = blockIdx.y * 256;
    const int wm = (wv >> 2) * 128;          // 0 or 128
    const int wn = (wv & 3) * 64;            // 0,64,128,192
    const int fr = lane & 15, fq = lane >> 4;
    const int hA = wm >> 7;
    const int hB = wn >> 7;
    const int NT = K >> 6;

    // ---- staging geometry (linear LDS dest; pre-swizzled global source) ----
    // lane covers linear half-offset L = (s*512 + wv*64 + lane)*16 bytes;
    // row(L) = s*64 + wv*8 + (lane>>3); LDS chunk (lane&7) holds global
    // chunk (lane&7)^(row&7).
    const int rs = wv * 8 + (lane >> 3);
    const int cg = ((lane & 7) ^ (rs & 7)) << 3;     // elements
    const s16* gs[2][2][2];                          // [op A/B][half][s]
    #pragma unroll
    for (int hh = 0; hh < 2; hh++) {
        gs[0][hh][0] = A  + (size_t)(m0 + hh * 128 + rs)      * K + cg;
        gs[0][hh][1] = A  + (size_t)(m0 + hh * 128 + rs + 64) * K + cg;
        gs[1][hh][0] = Bt + (size_t)(n0 + hh * 128 + rs)      * K + cg;
        gs[1][hh][1] = Bt + (size_t)(n0 + hh * 128 + rs + 64) * K + cg;
    }

    // ---- swizzled LDS read bases; frag rows have row&7 == fr&7 ----
    const int kx0 = (fq ^ (fr & 7)) << 4;    // byte offset, k2=0 chunk
    const int kx1 = kx0 ^ 64;                // k2=1 chunk (XOR, not add)
    const char* aBase[2] = {
        (const char*)&As[0][0] + hA * 16384 + fr * 128,
        (const char*)&As[1][0] + hA * 16384 + fr * 128 };
    const char* bBase[2] = {
        (const char*)&Bs[0][0] + hB * 16384 + ((wn & 64) + fr) * 128,
        (const char*)&Bs[1][0] + hB * 16384 + ((wn & 64) + fr) * 128 };

    f32x4 acc[8][4] = {};

    // ---- prologue: stage tile 0 into buf 0, drain, barrier ----
    #pragma unroll
    for (int u = 0; u < 4; u++) {
        const int op = u >> 1, hh = u & 1;
        s16* d = (op ? &Bs[0][0] : &As[0][0]) + hh * 8192 + wv * 512;
        gload16(gs[op][hh][0], d);
        gload16(gs[op][hh][1], d + 4096);
    }
    asm volatile("s_waitcnt vmcnt(0)");
    __builtin_amdgcn_sched_barrier(0);
    __builtin_amdgcn_s_barrier();

    short8 bf[4][2];
    for (int t = 0; t < NT; t++) {
        const int rb = t & 1, wb = rb ^ 1;
        const bool pre = (t + 1 < NT);
        #pragma unroll
        for (int q = 0; q < 4; q++) {
            // ds_read this phase's A-frags (mi = 2q, 2q+1), kk = 0,1
            short8 af[2][2];
            #pragma unroll
            for (int m2 = 0; m2 < 2; m2++)
                #pragma unroll
                for (int k2 = 0; k2 < 2; k2++)
                    af[m2][k2] = *(const short8*)(aBase[rb] + (2 * q + m2) * 2048
                                                  + (k2 ? kx1 : kx0));
            if (q == 0) {
                #pragma unroll
                for (int ni = 0; ni < 4; ni++)
                    #pragma unroll
                    for (int k2 = 0; k2 < 2; k2++)
                        bf[ni][k2] = *(const short8*)(bBase[rb] + ni * 2048
                                                      + (k2 ? kx1 : kx0));
            }
            // stage one quarter (16 KB half-tile) of tile t+1 into wb
            if (pre) {
                const int op = q >> 1, hh = q & 1;
                s16* d = (op ? &Bs[wb][0] : &As[wb][0]) + hh * 8192 + wv * 512;
                gload16(gs[op][hh][0] + (t + 1) * 64, d);
                gload16(gs[op][hh][1] + (t + 1) * 64, d + 4096);
            }
            __builtin_amdgcn_s_barrier();
            asm volatile("s_waitcnt lgkmcnt(0)");
            __builtin_amdgcn_sched_barrier(0);
            __builtin_amdgcn_s_setprio(1);
            #pragma unroll
            for (int m2 = 0; m2 < 2; m2++)
                #pragma unroll
                for (int ni = 0; ni < 4; ni++)
                    #pragma unroll
                    for (int k2 = 0; k2 < 2; k2++)
                        acc[2 * q + m2][ni] =
                            MFMA16(af[m2][k2], bf[ni][k2], acc[2 * q + m2][ni]);
            __builtin_amdgcn_s_setprio(0);
            if (q == 3) {     // once per K-tile: drain next tile's loads
                asm volatile("s_waitcnt vmcnt(0)");
                __builtin_amdgcn_sched_barrier(0);
            }
            __builtin_amdgcn_s_barrier();
        }
    }

    // ---- epilogue ----
    #pragma unroll
    for (int mi = 0; mi < 8; mi++)
        #pragma unroll
        for (int ni = 0; ni < 4; ni++)
            #pragma unroll
            for (int r = 0; r < 4; r++) {
                int m = m0 + wm + mi * 16 + fq * 4 + r;
                int n = n0 + wn + ni * 16 + fr;
                float v = acc[mi][ni][r];
                if (MODE == 0) {
                    if (n < 2048)
                        ((s16*)o0)[(size_t)m * 2048 + n] = f2bf(v + b0[n]);
                    else if (n < 2560)
                        ((s16*)o1)[(size_t)m * 512 + (n - 2048)] = f2bf(v + b1[n - 2048]);
                    else
                        ((s16*)o2)[(size_t)(n - 2560) * 4096 + m] = f2bf(v + b2[n - 2560]);
                } else {
                    ((float*)o0)[(size_t)m * N + n] = v + b0[n];
                }
            }
}

// ---------------------------------------------------------------------------
// Fused RoPE for Q (16 heads) and K (4 heads), in-place, pos 0.
// Blocks [0,16384) -> Qb rows; [16384,20480) -> Kb rows.
// ---------------------------------------------------------------------------
__global__ __launch_bounds__(256)
void rope2_kernel(s16* __restrict__ Qb, s16* __restrict__ Kb)
{
    int bx = blockIdx.x;
    s16* buf; int nheads; int idx;
    if (bx < 16384) { buf = Qb; nheads = 16; idx = bx * 256 + threadIdx.x; }
    else            { buf = Kb; nheads = 4;  idx = (bx - 16384) * 256 + threadIdx.x; }

    int i   = idx & 63;
    int hi  = idx >> 6;
    int h   = hi % nheads;
    int row = hi / nheads;
    int t   = row & 2047;

    float inv_freq = __powf(10000.0f, -(float)i * (1.0f / 64.0f));
    float ang = (float)t * inv_freq;
    float c = cosf(ang);
    float s = sinf(ang);

    size_t base = (size_t)row * ((size_t)nheads * 128) + (size_t)h * 128 + i;
    float x1 = bf2f(buf[base]);
    float x2 = bf2f(buf[base + 64]);
    buf[base]      = f2bf(x1 * c - x2 * s);
    buf[base + 64] = f2bf(x1 * s + x2 * c);
}

// ---------------------------------------------------------------------------
// Flash attention v3 (hybrid), sliding window + sink; both batches (z=b).
// Staging/pipeline = v1 (proven latency-hider): double-buffered K/V in LDS,
// register prefetch, 1 barrier per 32-key chunk, heavy-first dispatch.
// Softmax = v2 (proven correct, 4x less VALU): swapped QK^T (mfma(K,Q)->S^T)
// puts a q-row's 8 chunk scores in-lane; reduce = 7 fmax + 2 shfl; m/l state
// one scalar/lane (log2 domain); defer-max (THR=8) skips most O-rescales;
// P^T->A-frag staged via wave-private Ps (2x ds_write_b64, was 8x b16).
// setprio(1) wrapped around both MFMA clusters (T5, attn-proven).
// Q [4096][2048] bf16; Kb [4096][512]; Vt [512][4096]; At [2][2048][2048].
// ---------------------------------------------------------------------------
__global__ __launch_bounds__(256)
void attn_kernel(const s16* __restrict__ Q, const s16* __restrict__ Kb,
                 const s16* __restrict__ Vt, s16* __restrict__ At)
{
    __shared__ s16 Ks[2][32][136];   // [buf][key][d]
    __shared__ s16 Vs[2][128][40];   // [buf][d][key]
    __shared__ s16 Ps[4][16][40];    // [wave][q][key] P^T staging (wave-private)

    const int b = blockIdx.z;
    const int h = blockIdx.y, g = h >> 2;
    const int t0 = (31 - blockIdx.x) * 64;    // heavy blocks dispatch first
    const int tid = threadIdx.x, lane = tid & 63, wv = tid >> 6;
    const int fr = lane & 15, fq = lane >> 4;
    const int tw = t0 + wv * 16;
    s16* O = At + (size_t)b * 4194304;

    const float SCL2 = 0.12751743f;     // 128^-0.5 * log2(e)  (exp2 domain)
    const float NEG  = -1e9f;
    const float THR2 = 11.541560f;      // 8 * log2(e): defer-max threshold

    // per-thread staging geometry (2 chunks of work for K and V each)
    int kr[2], kc[2], vd[2], vc[2];
    const s16 *gK[2], *gV[2];
    #pragma unroll
    for (int it = 0; it < 2; it++) {
        int idx = it * 2048 + tid * 8;
        kr[it] = idx >> 7;  kc[it] = idx & 127;
        vd[it] = idx >> 5;  vc[it] = idx & 31;
        gK[it] = Kb + (size_t)(b * 2048 + kr[it]) * 512 + g * 128 + kc[it];
        gV[it] = Vt + (size_t)(g * 128 + vd[it]) * 4096 + b * 2048 + vc[it];
    }

    // Q as B-frag: B[k=fq*8+j][n=fr] = Q[tw+fr][d0+fq*8+j]  (whole kernel)
    short8 qf[4];
    {
        const s16* qrow = Q + (size_t)(b * 2048 + tw + fr) * 2048 + h * 128 + fq * 8;
        qf[0] = *(const short8*)(qrow);
        qf[1] = *(const short8*)(qrow + 32);
        qf[2] = *(const short8*)(qrow + 64);
        qf[3] = *(const short8*)(qrow + 96);
    }

    f32x4 Oacc[8] = {};
    float m2 = NEG, l_s = 0.0f;         // softmax state for q = tw + fr
    const int tq = tw + fr;

    int lo = t0 - 512; if (lo < 0) lo = 0;
    const int c0   = lo >> 5;
    const int cend = (t0 + 63) >> 5;
    const int nch  = cend - c0 + 1 + (c0 > 0 ? 1 : 0);

    #define CHUNKBASE(ic) ((((c0) > 0) ? ((ic) == 0 ? 0 : c0 + (ic) - 1) : (ic)) * 32)

    short8 kpre[2], vpre[2];
    {   // prefetch + store chunk 0 into buf 0
        int kb = CHUNKBASE(0);
        #pragma unroll
        for (int it = 0; it < 2; it++) {
            kpre[it] = *(const short8*)(gK[it] + (size_t)kb * 512);
            vpre[it] = *(const short8*)(gV[it] + kb);
        }
        #pragma unroll
        for (int it = 0; it < 2; it++) {
            *(short8*)&Ks[0][kr[it]][kc[it]] = kpre[it];
            *(short8*)&Vs[0][vd[it]][vc[it]] = vpre[it];
        }
    }
    __syncthreads();

    for (int ic = 0; ic < nch; ic++) {
        const int cur = ic & 1;
        const int kbase = CHUNKBASE(ic);
        const bool pre = (ic + 1 < nch);
        if (pre) {
            int kb = CHUNKBASE(ic + 1);
            #pragma unroll
            for (int it = 0; it < 2; it++) {
                kpre[it] = *(const short8*)(gK[it] + (size_t)kb * 512);
                vpre[it] = *(const short8*)(gV[it] + kb);
            }
        }

        // S^T = K Q^T : C row = key (kn*16 + fq*4 + r), col = q (fr).
        f32x4 sc[2] = {{0.f,0.f,0.f,0.f},{0.f,0.f,0.f,0.f}};
        __builtin_amdgcn_s_setprio(1);
        #pragma unroll
        for (int kn = 0; kn < 2; kn++)
            #pragma unroll
            for (int dc = 0; dc < 4; dc++) {
                short8 kf = *(const short8*)&Ks[cur][kn * 16 + fr][dc * 32 + fq * 8];
                sc[kn] = MFMA16(kf, qf[dc], sc[kn]);
            }
        __builtin_amdgcn_s_setprio(0);

        // mask + scale into log2 domain; all 8 values belong to q = tq
        float sv[8];
        #pragma unroll
        for (int kn = 0; kn < 2; kn++)
            #pragma unroll
            for (int r = 0; r < 4; r++) {
                int j = kbase + kn * 16 + fq * 4 + r;
                bool ok = (j <= tq) && ((j >= tq - 512) || (j < 4));
                sv[kn * 4 + r] = ok ? sc[kn][r] * SCL2 : NEG;
            }

        // chunk max for this q-row: in-lane over 8, then across the 4 fq groups
        float cm = fmaxf(sv[0], sv[1]);
        #pragma unroll
        for (int i = 2; i < 8; i++) cm = fmaxf(cm, sv[i]);
        cm = fmaxf(cm, __shfl_xor(cm, 16));
        cm = fmaxf(cm, __shfl_xor(cm, 32));

        // defer-max: only rescale when some row grew by > THR2
        if (__any(cm > m2 + THR2)) {
            float nm    = fmaxf(m2, cm);
            float alpha = exp2f(m2 - nm);
            m2  = nm;
            l_s *= alpha;
            #pragma unroll
            for (int r = 0; r < 4; r++) {
                float ar = __shfl(alpha, (lane & 48) + fq * 4 + r);
                #pragma unroll
                for (int n0 = 0; n0 < 8; n0++) Oacc[n0][r] *= ar;
            }
        }

        float p[8], ps = 0.0f;
        #pragma unroll
        for (int i = 0; i < 8; i++) { p[i] = exp2f(sv[i] - m2); ps += p[i]; }
        ps += __shfl_xor(ps, 16);
        ps += __shfl_xor(ps, 32);
        l_s += ps;

        // P^T (C layout [key][q]) -> Ps[q][key] so pf reads an A-frag
        s16x4 w0, w1;
        #pragma unroll
        for (int r = 0; r < 4; r++) { w0[r] = f2bf(p[r]); w1[r] = f2bf(p[4 + r]); }
        *(s16x4*)&Ps[wv][fr][fq * 4]      = w0;   // keys kn=0: fq*4..fq*4+3
        *(s16x4*)&Ps[wv][fr][16 + fq * 4] = w1;   // keys kn=1
        __threadfence_block();
        short8 pf = *(const short8*)&Ps[wv][fr][fq * 8];  // A[m=q][k=key]

        __builtin_amdgcn_s_setprio(1);
        #pragma unroll
        for (int n0 = 0; n0 < 8; n0++) {
            short8 vf = *(const short8*)&Vs[cur][n0 * 16 + fr][fq * 8];
            Oacc[n0] = MFMA16(pf, vf, Oacc[n0]);
        }
        __builtin_amdgcn_s_setprio(0);

        if (pre) {
            #pragma unroll
            for (int it = 0; it < 2; it++) {
                *(short8*)&Ks[cur ^ 1][kr[it]][kc[it]] = kpre[it];
                *(short8*)&Vs[cur ^ 1][vd[it]][vc[it]] = vpre[it];
            }
            __syncthreads();
        }
    }

    // epilogue: l for Oacc row fq*4+r lives at lane fq*16 + (fq*4+r)
    float linv[4];
    #pragma unroll
    for (int r = 0; r < 4; r++)
        linv[r] = 1.0f / __shfl(l_s, (lane & 48) + fq * 4 + r);
    #pragma unroll
    for (int n0 = 0; n0 < 8; n0++)
        #pragma unroll
        for (int r = 0; r < 4; r++) {
            int t = tw + fq * 4 + r;
            O[(size_t)t * 2048 + h * 128 + n0 * 16 + fr] =
                f2bf(Oacc[n0][r] * linv[r]);
        }
}

// ---------------------------------------------------------------------------
// Launcher (memory map at top of file).
// ---------------------------------------------------------------------------
extern "C" void kernel_launch(void* const* d_in, const int* in_sizes, int n_in,
                              void* d_out, int out_size, void* d_ws, size_t ws_size,
                              hipStream_t stream)
{
    const float* x  = (const float*)d_in[0];
    const float* Wq = (const float*)d_in[1];
    const float* bq = (const float*)d_in[2];
    const float* Wk = (const float*)d_in[3];
    const float* bk = (const float*)d_in[4];
    const float* Wv = (const float*)d_in[5];
    const float* bv = (const float*)d_in[6];
    const float* Wo = (const float*)d_in[7];
    const float* bo = (const float*)d_in[8];
    float* out = (float*)d_out;

    if (ws_size < 33554432) return;

    char* ws = (char*)d_ws;
    s16* xb    = (s16*)(ws + 0);           // [4096][2048] bf16 (16 MB)
    s16* At    = (s16*)(ws + 0);           // [2][2048][2048] bf16 (after xb dies)
    s16* Wqkvt = (s16*)(ws + 16777216);    // [3072][2048] bf16 (12 MB)
    s16* Wot   = (s16*)(ws + 16777216);    // [2048][2048] bf16 (after QKV GEMM)
    s16* Qb    = (s16*)d_out;                              // [4096][2048] bf16
    s16* Kb    = (s16*)((char*)d_out + 16777216);          // [4096][512]  bf16
    s16* Vt    = (s16*)((char*)d_out + 20971520);          // [512][4096]  bf16

    // x -> bf16
    cast_bf16<<<4096, 256, 0, stream>>>(x, xb);

    // QKV weights -> Wqkvt (transposed bf16)
    castT3<<<dim3(64, 64, 3), 256, 0, stream>>>(Wq, Wk, Wv, Wqkvt);

    // fused QKV projection with split epilogue (256^2 tiles, 512 thr)
    gemm256<0><<<dim3(16, 12), 512, 0, stream>>>(xb, Wqkvt, bq, bk, bv,
                                                 Qb, Kb, Vt, 4096, 3072, 2048);

    // RoPE on Q and K (one launch)
    rope2_kernel<<<20480, 256, 0, stream>>>(Qb, Kb);

    // O weight (overwrites Wqkvt; stream-ordered after QKV GEMM)
    castT<<<dim3(64, 64), 256, 0, stream>>>(Wo, Wot);

    // attention, both batches (xb dead -> At reuses its space)
    attn_kernel<<<dim3(32, 16, 2), 256, 0, stream>>>(Qb, Kb, Vt, At);

    // output projection: At [4096][2048] x Wot + bo -> out fp32
    gemm256<2><<<dim3(16, 8), 512, 0, stream>>>(At, Wot, bo, nullptr, nullptr,
                                                out, nullptr, nullptr,
                                                4096, 2048, 2048);
}

// Round 6
// 374.077 us; speedup vs baseline: 1.3187x; 1.3187x over previous
//
#include <hip/hip_runtime.h>
#include <hip/hip_bf16.h>
#include <cstdint>
#include <cstddef>

// ---------------------------------------------------------------------------
// MaskedSelfAttention: B=2, T=2048, C=2048, NH=16, NG=4, D=128
// sliding window 512 + sink 4, RoPE base 10000, pos 0.
// fp32 I/O; bf16 MFMA internally (fp32 accum).
// Workspace (32 MB):
//   [0,16M):  xb [4096][2048] bf16 -> later At [2][2048][2048] bf16
//   [16,28M): Wqkvt [3072][2048] bf16 -> later Wot [2048][2048] (16-24M)
// d_out scratch (33.5 MB fp32, dead until final O-GEMM):
//   [0,16.78M): Qb [4096][2048] bf16
//   [16.78,20.97M): Kb [4096][512] bf16
//   [20.97,25.17M): Vt [512][4096] bf16
// ---------------------------------------------------------------------------

typedef short s16;
typedef short short8 __attribute__((ext_vector_type(8)));
typedef short s16x4  __attribute__((ext_vector_type(4)));
typedef float f32x4  __attribute__((ext_vector_type(4)));

#define MFMA16(a, b, c) __builtin_amdgcn_mfma_f32_16x16x32_bf16((a), (b), (c), 0, 0, 0)

__device__ __forceinline__ float bf2f(s16 u) {
    union { float f; uint32_t i; } v;
    v.i = ((uint32_t)(uint16_t)u) << 16;
    return v.f;
}
__device__ __forceinline__ s16 f2bf(float f) {
    union { float f; uint32_t i; } v;
    v.f = f;
    uint32_t r = v.i + 0x7FFFu + ((v.i >> 16) & 1u);   // RNE
    return (s16)(r >> 16);
}

// async global->LDS, 16 B per lane; LDS dest = wave-uniform base + lane*16
__device__ __forceinline__ void gload16(const s16* g, s16* l) {
    __builtin_amdgcn_global_load_lds(
        (const __attribute__((address_space(1))) void*)g,
        (__attribute__((address_space(3))) void*)l, 16, 0, 0);
}

// ---------------------------------------------------------------------------
// Elementwise fp32 -> bf16 cast (8 elems/thread).
// ---------------------------------------------------------------------------
__global__ __launch_bounds__(256)
void cast_bf16(const float* __restrict__ in, s16* __restrict__ out)
{
    size_t i = ((size_t)blockIdx.x * 256 + threadIdx.x) * 8;
    f32x4 f0 = *(const f32x4*)(in + i);
    f32x4 f1 = *(const f32x4*)(in + i + 4);
    short8 h;
    h[0]=f2bf(f0[0]); h[1]=f2bf(f0[1]); h[2]=f2bf(f0[2]); h[3]=f2bf(f0[3]);
    h[4]=f2bf(f1[0]); h[5]=f2bf(f1[1]); h[6]=f2bf(f1[2]); h[7]=f2bf(f1[3]);
    *(short8*)(out + i) = h;
}

// ---------------------------------------------------------------------------
// Transpose+cast all three QKV weights into Wqkvt [3072][2048]:
//   rows 0-2047 = Wq^T, 2048-2559 = Wk^T, 2560-3071 = Wv^T. K=2048 fixed.
// ---------------------------------------------------------------------------
__global__ __launch_bounds__(256)
void castT3(const float* __restrict__ Wq, const float* __restrict__ Wk,
            const float* __restrict__ Wv, s16* __restrict__ out)
{
    int z = blockIdx.z;
    const float* in; s16* dst; int N;
    if (z == 0)      { in = Wq; dst = out;                        N = 2048; }
    else if (z == 1) { in = Wk; dst = out + (size_t)2048 * 2048;  N = 512; }
    else             { in = Wv; dst = out + (size_t)2560 * 2048;  N = 512; }
    int n0 = blockIdx.x * 32, k0 = blockIdx.y * 32;
    if (n0 >= N) return;

    __shared__ float t[32][33];
    int tx = threadIdx.x & 31, ty = threadIdx.x >> 5;
    for (int i = 0; i < 32; i += 8)
        t[ty + i][tx] = in[(size_t)(k0 + ty + i) * N + n0 + tx];
    __syncthreads();
    for (int i = 0; i < 32; i += 8)
        dst[(size_t)(n0 + ty + i) * 2048 + k0 + tx] = f2bf(t[tx][ty + i]);
}

// ---------------------------------------------------------------------------
// Single-weight transpose+cast: fp32 [2048][2048] -> bf16 [2048][2048]^T.
// ---------------------------------------------------------------------------
__global__ __launch_bounds__(256)
void castT(const float* __restrict__ in, s16* __restrict__ out)
{
    __shared__ float t[32][33];
    int n0 = blockIdx.x * 32, k0 = blockIdx.y * 32;
    int tx = threadIdx.x & 31, ty = threadIdx.x >> 5;
    for (int i = 0; i < 32; i += 8)
        t[ty + i][tx] = in[(size_t)(k0 + ty + i) * 2048 + n0 + tx];
    __syncthreads();
    for (int i = 0; i < 32; i += 8)
        out[(size_t)(n0 + ty + i) * 2048 + k0 + tx] = f2bf(t[tx][ty + i]);
}

// ---------------------------------------------------------------------------
// GEMM v5 "ring": out = A[M][K] x Bt[N][K]^T + bias.
// Tile 128x128, BK=32, 256 thr = 4 waves (2Mx2N), wave C = 64x64 (4x4 frags).
// T4 counted-vmcnt pipeline (the piece v4 got wrong; m218: counted vs drain0
// = +38-73%):
//  - LDS ring of FOUR 8 KB buffers per operand (64 KB total -> 2 blocks/CU).
//    Tile t+2 is staged (4x gload16/thread) while tile t computes; the
//    per-tile wait is vmcnt(4) -- tile t+1's loads complete, tile t+2's 4
//    stay in flight ACROSS the barrier. Drain-0 only in the last 2 tiles.
//    Stage->read distance = 2 full tiles (~2x16 MFMA + 2 barriers of cover).
//  - One barrier per K-tile (m97 had 2 + full vmcnt(0) drain = its ~20%).
//  - Bank-conflict-free swizzle (validated model: conflicts resolve per
//    16-lane issue group; v4b's measured 0 conflicts confirms):
//    global 16B-chunk c of row r stored at LDS chunk c ^ (r&3) ^ ((r>>2)&3)
//    (involution; applied on the pre-swizzled global source, rule #21).
//    Frag reads: rows wm+mi*16+fr have r&3=fr&3 and (r>>2)&3=(fr>>2)&3, so
//    the read XOR is a per-lane constant; per-16-lane-group enumeration:
//    8 slots x 2 lanes = 2-way = free (m136).
// MODE 0: QKV split epilogue (n<2048 -> Qb bf16; n<2560 -> Kb bf16;
//         else Vt bf16 transposed).  MODE 2: fp32 out + bias.
// mfma_f32_16x16x32_bf16 layouts (verified m89/m91):
//   A-frag: A[m=lane&15][k=(lane>>4)*8+j]; B-frag: B[k=(lane>>4)*8+j][n=lane&15]
//   C/D:    row=(lane>>4)*4+reg, col=lane&15
// ---------------------------------------------------------------------------
template <int MODE>
__global__ __launch_bounds__(256, 2)
void gemm_ring(const s16* __restrict__ A, const s16* __restrict__ Bt,
               const float* __restrict__ b0, const float* __restrict__ b1,
               const float* __restrict__ b2,
               void* __restrict__ o0, void* __restrict__ o1, void* __restrict__ o2,
               int M, int N, int K)
{
    __shared__ s16 As[4][4096];   // ring: 4 bufs x [128 rows][32 cols] bf16
    __shared__ s16 Bs[4][4096];

    const int tid  = threadIdx.x;
    const int lane = tid & 63, wv = tid >> 6;
    const int m0 = blockIdx.x * 128, n0 = blockIdx.y * 128;
    const int wm = (wv >> 1) * 64, wn = (wv & 1) * 64;
    const int fr = lane & 15, fq = lane >> 4;
    const int NT = K >> 5;

    // ---- staging geometry: thread covers rows s*64+(tid>>2), chunk tid&3 of
    // each 64B row; pre-swizzled source chunk cg = (tid&3)^((tid>>2)&3)^((tid>>4)&3)
    // (r&3=(tid>>2)&3; (r>>2)&3=(tid>>4)&3 since s*16===0 mod 4).
    const int rsub = tid >> 2;
    const int cg = (((tid & 3) ^ ((tid >> 2) & 3) ^ ((tid >> 4) & 3))) << 3;  // elems
    const s16* gA0 = A  + (size_t)(m0 + rsub) * K + cg;
    const s16* gA1 = A  + (size_t)(m0 + 64 + rsub) * K + cg;
    const s16* gB0 = Bt + (size_t)(n0 + rsub) * K + cg;
    const s16* gB1 = Bt + (size_t)(n0 + 64 + rsub) * K + cg;

    // ---- swizzled read bases: chunk fq of row r at byte r*64 + ((fq^(r&3)^((r>>2)&3))<<4)
    const int kxr = ((fq ^ (fr & 3) ^ ((fr >> 2) & 3)) << 4);
    const char* aRow = (const char*)As + (wm + fr) * 64 + kxr;
    const char* bRow = (const char*)Bs + (wn + fr) * 64 + kxr;

    f32x4 acc[4][4] = {};

#define STAGE(tt) do { const int _bi = (tt) & 3;                             \
        s16* _da = &As[_bi][0] + wv * 512;                                   \
        s16* _db = &Bs[_bi][0] + wv * 512;                                   \
        gload16(gA0 + (tt) * 32, _da);                                       \
        gload16(gA1 + (tt) * 32, _da + 2048);                                \
        gload16(gB0 + (tt) * 32, _db);                                       \
        gload16(gB1 + (tt) * 32, _db + 2048); } while (0)

    // ---- prologue: stage tiles 0,1; wait tile 0 only (vmcnt(4)) ----
    STAGE(0);
    STAGE(1);
    asm volatile("s_waitcnt vmcnt(4)");
    __builtin_amdgcn_sched_barrier(0);
    __builtin_amdgcn_s_barrier();

    for (int t = 0; t < NT; t++) {
        const int rb = t & 3;
        if (t + 2 < NT) STAGE(t + 2);        // issue-early: 2 tiles ahead

        short8 af[4], bfr[4];
        const char* aP = aRow + rb * 8192;
        const char* bP = bRow + rb * 8192;
        #pragma unroll
        for (int i = 0; i < 4; i++) af[i]  = *(const short8*)(aP + i * 1024);
        #pragma unroll
        for (int i = 0; i < 4; i++) bfr[i] = *(const short8*)(bP + i * 1024);

        asm volatile("s_waitcnt lgkmcnt(0)");
        __builtin_amdgcn_sched_barrier(0);
        __builtin_amdgcn_s_setprio(1);
        #pragma unroll
        for (int mi = 0; mi < 4; mi++)
            #pragma unroll
            for (int ni = 0; ni < 4; ni++)
                acc[mi][ni] = MFMA16(af[mi], bfr[ni], acc[mi][ni]);
        __builtin_amdgcn_s_setprio(0);

        if (t + 1 < NT) {
            __builtin_amdgcn_sched_barrier(0);
            if (t + 2 < NT) asm volatile("s_waitcnt vmcnt(4)");  // counted: t+1 done,
            else            asm volatile("s_waitcnt vmcnt(0)");  // t+2 stays in flight
            __builtin_amdgcn_sched_barrier(0);
            __builtin_amdgcn_s_barrier();
        }
    }
#undef STAGE

    // ---- epilogue ----
    #pragma unroll
    for (int mi = 0; mi < 4; mi++)
        #pragma unroll
        for (int ni = 0; ni < 4; ni++)
            #pragma unroll
            for (int r = 0; r < 4; r++) {
                int m = m0 + wm + mi * 16 + fq * 4 + r;
                int n = n0 + wn + ni * 16 + fr;
                float v = acc[mi][ni][r];
                if (MODE == 0) {
                    if (n < 2048)
                        ((s16*)o0)[(size_t)m * 2048 + n] = f2bf(v + b0[n]);
                    else if (n < 2560)
                        ((s16*)o1)[(size_t)m * 512 + (n - 2048)] = f2bf(v + b1[n - 2048]);
                    else
                        ((s16*)o2)[(size_t)(n - 2560) * 4096 + m] = f2bf(v + b2[n - 2560]);
                } else {
                    ((float*)o0)[(size_t)m * N + n] = v + b0[n];
                }
            }
}

// ---------------------------------------------------------------------------
// Fused RoPE for Q (16 heads) and K (4 heads), in-place, pos 0.
// Blocks [0,16384) -> Qb rows; [16384,20480) -> Kb rows.
// ---------------------------------------------------------------------------
__global__ __launch_bounds__(256)
void rope2_kernel(s16* __restrict__ Qb, s16* __restrict__ Kb)
{
    int bx = blockIdx.x;
    s16* buf; int nheads; int idx;
    if (bx < 16384) { buf = Qb; nheads = 16; idx = bx * 256 + threadIdx.x; }
    else            { buf = Kb; nheads = 4;  idx = (bx - 16384) * 256 + threadIdx.x; }

    int i   = idx & 63;
    int hi  = idx >> 6;
    int h   = hi % nheads;
    int row = hi / nheads;
    int t   = row & 2047;

    float inv_freq = __powf(10000.0f, -(float)i * (1.0f / 64.0f));
    float ang = (float)t * inv_freq;
    float c = cosf(ang);
    float s = sinf(ang);

    size_t base = (size_t)row * ((size_t)nheads * 128) + (size_t)h * 128 + i;
    float x1 = bf2f(buf[base]);
    float x2 = bf2f(buf[base + 64]);
    buf[base]      = f2bf(x1 * c - x2 * s);
    buf[base + 64] = f2bf(x1 * s + x2 * c);
}

// ---------------------------------------------------------------------------
// Flash attention v3 (hybrid), sliding window + sink; both batches (z=b).
// Staging/pipeline = v1 (proven latency-hider): double-buffered K/V in LDS,
// register prefetch, 1 barrier per 32-key chunk, heavy-first dispatch.
// Softmax = v2 (proven correct, 4x less VALU): swapped QK^T (mfma(K,Q)->S^T)
// puts a q-row's 8 chunk scores in-lane; reduce = 7 fmax + 2 shfl; m/l state
// one scalar/lane (log2 domain); defer-max (THR=8) skips most O-rescales;
// P^T->A-frag staged via wave-private Ps (2x ds_write_b64, was 8x b16).
// setprio(1) wrapped around both MFMA clusters (T5, attn-proven).
// Q [4096][2048] bf16; Kb [4096][512]; Vt [512][4096]; At [2][2048][2048].
// ---------------------------------------------------------------------------
__global__ __launch_bounds__(256)
void attn_kernel(const s16* __restrict__ Q, const s16* __restrict__ Kb,
                 const s16* __restrict__ Vt, s16* __restrict__ At)
{
    __shared__ s16 Ks[2][32][136];   // [buf][key][d]
    __shared__ s16 Vs[2][128][40];   // [buf][d][key]
    __shared__ s16 Ps[4][16][40];    // [wave][q][key] P^T staging (wave-private)

    const int b = blockIdx.z;
    const int h = blockIdx.y, g = h >> 2;
    const int t0 = (31 - blockIdx.x) * 64;    // heavy blocks dispatch first
    const int tid = threadIdx.x, lane = tid & 63, wv = tid >> 6;
    const int fr = lane & 15, fq = lane >> 4;
    const int tw = t0 + wv * 16;
    s16* O = At + (size_t)b * 4194304;

    const float SCL2 = 0.12751743f;     // 128^-0.5 * log2(e)  (exp2 domain)
    const float NEG  = -1e9f;
    const float THR2 = 11.541560f;      // 8 * log2(e): defer-max threshold

    // per-thread staging geometry (2 chunks of work for K and V each)
    int kr[2], kc[2], vd[2], vc[2];
    const s16 *gK[2], *gV[2];
    #pragma unroll
    for (int it = 0; it < 2; it++) {
        int idx = it * 2048 + tid * 8;
        kr[it] = idx >> 7;  kc[it] = idx & 127;
        vd[it] = idx >> 5;  vc[it] = idx & 31;
        gK[it] = Kb + (size_t)(b * 2048 + kr[it]) * 512 + g * 128 + kc[it];
        gV[it] = Vt + (size_t)(g * 128 + vd[it]) * 4096 + b * 2048 + vc[it];
    }

    // Q as B-frag: B[k=fq*8+j][n=fr] = Q[tw+fr][d0+fq*8+j]  (whole kernel)
    short8 qf[4];
    {
        const s16* qrow = Q + (size_t)(b * 2048 + tw + fr) * 2048 + h * 128 + fq * 8;
        qf[0] = *(const short8*)(qrow);
        qf[1] = *(const short8*)(qrow + 32);
        qf[2] = *(const short8*)(qrow + 64);
        qf[3] = *(const short8*)(qrow + 96);
    }

    f32x4 Oacc[8] = {};
    float m2 = NEG, l_s = 0.0f;         // softmax state for q = tw + fr
    const int tq = tw + fr;

    int lo = t0 - 512; if (lo < 0) lo = 0;
    const int c0   = lo >> 5;
    const int cend = (t0 + 63) >> 5;
    const int nch  = cend - c0 + 1 + (c0 > 0 ? 1 : 0);

    #define CHUNKBASE(ic) ((((c0) > 0) ? ((ic) == 0 ? 0 : c0 + (ic) - 1) : (ic)) * 32)

    short8 kpre[2], vpre[2];
    {   // prefetch + store chunk 0 into buf 0
        int kb = CHUNKBASE(0);
        #pragma unroll
        for (int it = 0; it < 2; it++) {
            kpre[it] = *(const short8*)(gK[it] + (size_t)kb * 512);
            vpre[it] = *(const short8*)(gV[it] + kb);
        }
        #pragma unroll
        for (int it = 0; it < 2; it++) {
            *(short8*)&Ks[0][kr[it]][kc[it]] = kpre[it];
            *(short8*)&Vs[0][vd[it]][vc[it]] = vpre[it];
        }
    }
    __syncthreads();

    for (int ic = 0; ic < nch; ic++) {
        const int cur = ic & 1;
        const int kbase = CHUNKBASE(ic);
        const bool pre = (ic + 1 < nch);
        if (pre) {
            int kb = CHUNKBASE(ic + 1);
            #pragma unroll
            for (int it = 0; it < 2; it++) {
                kpre[it] = *(const short8*)(gK[it] + (size_t)kb * 512);
                vpre[it] = *(const short8*)(gV[it] + kb);
            }
        }

        // S^T = K Q^T : C row = key (kn*16 + fq*4 + r), col = q (fr).
        f32x4 sc[2] = {{0.f,0.f,0.f,0.f},{0.f,0.f,0.f,0.f}};
        __builtin_amdgcn_s_setprio(1);
        #pragma unroll
        for (int kn = 0; kn < 2; kn++)
            #pragma unroll
            for (int dc = 0; dc < 4; dc++) {
                short8 kf = *(const short8*)&Ks[cur][kn * 16 + fr][dc * 32 + fq * 8];
                sc[kn] = MFMA16(kf, qf[dc], sc[kn]);
            }
        __builtin_amdgcn_s_setprio(0);

        // mask + scale into log2 domain; all 8 values belong to q = tq
        float sv[8];
        #pragma unroll
        for (int kn = 0; kn < 2; kn++)
            #pragma unroll
            for (int r = 0; r < 4; r++) {
                int j = kbase + kn * 16 + fq * 4 + r;
                bool ok = (j <= tq) && ((j >= tq - 512) || (j < 4));
                sv[kn * 4 + r] = ok ? sc[kn][r] * SCL2 : NEG;
            }

        // chunk max for this q-row: in-lane over 8, then across the 4 fq groups
        float cm = fmaxf(sv[0], sv[1]);
        #pragma unroll
        for (int i = 2; i < 8; i++) cm = fmaxf(cm, sv[i]);
        cm = fmaxf(cm, __shfl_xor(cm, 16));
        cm = fmaxf(cm, __shfl_xor(cm, 32));

        // defer-max: only rescale when some row grew by > THR2
        if (__any(cm > m2 + THR2)) {
            float nm    = fmaxf(m2, cm);
            float alpha = exp2f(m2 - nm);
            m2  = nm;
            l_s *= alpha;
            #pragma unroll
            for (int r = 0; r < 4; r++) {
                float ar = __shfl(alpha, (lane & 48) + fq * 4 + r);
                #pragma unroll
                for (int n0 = 0; n0 < 8; n0++) Oacc[n0][r] *= ar;
            }
        }

        float p[8], ps = 0.0f;
        #pragma unroll
        for (int i = 0; i < 8; i++) { p[i] = exp2f(sv[i] - m2); ps += p[i]; }
        ps += __shfl_xor(ps, 16);
        ps += __shfl_xor(ps, 32);
        l_s += ps;

        // P^T (C layout [key][q]) -> Ps[q][key] so pf reads an A-frag
        s16x4 w0, w1;
        #pragma unroll
        for (int r = 0; r < 4; r++) { w0[r] = f2bf(p[r]); w1[r] = f2bf(p[4 + r]); }
        *(s16x4*)&Ps[wv][fr][fq * 4]      = w0;   // keys kn=0: fq*4..fq*4+3
        *(s16x4*)&Ps[wv][fr][16 + fq * 4] = w1;   // keys kn=1
        __threadfence_block();
        short8 pf = *(const short8*)&Ps[wv][fr][fq * 8];  // A[m=q][k=key]

        __builtin_amdgcn_s_setprio(1);
        #pragma unroll
        for (int n0 = 0; n0 < 8; n0++) {
            short8 vf = *(const short8*)&Vs[cur][n0 * 16 + fr][fq * 8];
            Oacc[n0] = MFMA16(pf, vf, Oacc[n0]);
        }
        __builtin_amdgcn_s_setprio(0);

        if (pre) {
            #pragma unroll
            for (int it = 0; it < 2; it++) {
                *(short8*)&Ks[cur ^ 1][kr[it]][kc[it]] = kpre[it];
                *(short8*)&Vs[cur ^ 1][vd[it]][vc[it]] = vpre[it];
            }
            __syncthreads();
        }
    }

    // epilogue: l for Oacc row fq*4+r lives at lane fq*16 + (fq*4+r)
    float linv[4];
    #pragma unroll
    for (int r = 0; r < 4; r++)
        linv[r] = 1.0f / __shfl(l_s, (lane & 48) + fq * 4 + r);
    #pragma unroll
    for (int n0 = 0; n0 < 8; n0++)
        #pragma unroll
        for (int r = 0; r < 4; r++) {
            int t = tw + fq * 4 + r;
            O[(size_t)t * 2048 + h * 128 + n0 * 16 + fr] =
                f2bf(Oacc[n0][r] * linv[r]);
        }
}

// ---------------------------------------------------------------------------
// Launcher (memory map at top of file).
// ---------------------------------------------------------------------------
extern "C" void kernel_launch(void* const* d_in, const int* in_sizes, int n_in,
                              void* d_out, int out_size, void* d_ws, size_t ws_size,
                              hipStream_t stream)
{
    const float* x  = (const float*)d_in[0];
    const float* Wq = (const float*)d_in[1];
    const float* bq = (const float*)d_in[2];
    const float* Wk = (const float*)d_in[3];
    const float* bk = (const float*)d_in[4];
    const float* Wv = (const float*)d_in[5];
    const float* bv = (const float*)d_in[6];
    const float* Wo = (const float*)d_in[7];
    const float* bo = (const float*)d_in[8];
    float* out = (float*)d_out;

    if (ws_size < 33554432) return;

    char* ws = (char*)d_ws;
    s16* xb    = (s16*)(ws + 0);           // [4096][2048] bf16 (16 MB)
    s16* At    = (s16*)(ws + 0);           // [2][2048][2048] bf16 (after xb dies)
    s16* Wqkvt = (s16*)(ws + 16777216);    // [3072][2048] bf16 (12 MB)
    s16* Wot   = (s16*)(ws + 16777216);    // [2048][2048] bf16 (after QKV GEMM)
    s16* Qb    = (s16*)d_out;                              // [4096][2048] bf16
    s16* Kb    = (s16*)((char*)d_out + 16777216);          // [4096][512]  bf16
    s16* Vt    = (s16*)((char*)d_out + 20971520);          // [512][4096]  bf16

    // x -> bf16
    cast_bf16<<<4096, 256, 0, stream>>>(x, xb);

    // QKV weights -> Wqkvt (transposed bf16)
    castT3<<<dim3(64, 64, 3), 256, 0, stream>>>(Wq, Wk, Wv, Wqkvt);

    // fused QKV projection with split epilogue (128^2 tiles, ring pipeline)
    gemm_ring<0><<<dim3(32, 24), 256, 0, stream>>>(xb, Wqkvt, bq, bk, bv,
                                                   Qb, Kb, Vt, 4096, 3072, 2048);

    // RoPE on Q and K (one launch)
    rope2_kernel<<<20480, 256, 0, stream>>>(Qb, Kb);

    // O weight (overwrites Wqkvt; stream-ordered after QKV GEMM)
    castT<<<dim3(64, 64), 256, 0, stream>>>(Wo, Wot);

    // attention, both batches (xb dead -> At reuses its space)
    attn_kernel<<<dim3(32, 16, 2), 256, 0, stream>>>(Qb, Kb, Vt, At);

    // output projection: At [4096][2048] x Wot + bo -> out fp32
    gemm_ring<2><<<dim3(32, 16), 256, 0, stream>>>(At, Wot, bo, nullptr, nullptr,
                                                   out, nullptr, nullptr,
                                                   4096, 2048, 2048);
}

// Round 7
// 311.395 us; speedup vs baseline: 1.5842x; 1.2013x over previous
//
#include <hip/hip_runtime.h>
#include <hip/hip_bf16.h>
#include <cstdint>
#include <cstddef>

// ---------------------------------------------------------------------------
// MaskedSelfAttention: B=2, T=2048, C=2048, NH=16, NG=4, D=128
// sliding window 512 + sink 4, RoPE base 10000, pos 0.
// fp32 I/O; bf16 MFMA internally (fp32 accum).
// Workspace (32 MB):
//   [0,16M):  xb [4096][2048] bf16 -> later At [2][2048][2048] bf16
//   [16,28M): Wqkvt [3072][2048] bf16 -> later Wot [2048][2048] (16-24M)
// d_out scratch (33.5 MB fp32, dead until final O-GEMM):
//   [0,16.78M): Qb [4096][2048] bf16
//   [16.78,20.97M): Kb [4096][512] bf16
//   [20.97,25.17M): Vt [512][4096] bf16
// ---------------------------------------------------------------------------

typedef short s16;
typedef short short8 __attribute__((ext_vector_type(8)));
typedef short s16x4  __attribute__((ext_vector_type(4)));
typedef float f32x4  __attribute__((ext_vector_type(4)));

#define MFMA16(a, b, c) __builtin_amdgcn_mfma_f32_16x16x32_bf16((a), (b), (c), 0, 0, 0)

__device__ __forceinline__ float bf2f(s16 u) {
    union { float f; uint32_t i; } v;
    v.i = ((uint32_t)(uint16_t)u) << 16;
    return v.f;
}
__device__ __forceinline__ s16 f2bf(float f) {
    union { float f; uint32_t i; } v;
    v.f = f;
    uint32_t r = v.i + 0x7FFFu + ((v.i >> 16) & 1u);   // RNE
    return (s16)(r >> 16);
}

// async global->LDS, 16 B per lane; LDS dest = wave-uniform base + lane*16
__device__ __forceinline__ void gload16(const s16* g, s16* l) {
    __builtin_amdgcn_global_load_lds(
        (const __attribute__((address_space(1))) void*)g,
        (__attribute__((address_space(3))) void*)l, 16, 0, 0);
}

// ---------------------------------------------------------------------------
// Elementwise fp32 -> bf16 cast (8 elems/thread).
// ---------------------------------------------------------------------------
__global__ __launch_bounds__(256)
void cast_bf16(const float* __restrict__ in, s16* __restrict__ out)
{
    size_t i = ((size_t)blockIdx.x * 256 + threadIdx.x) * 8;
    f32x4 f0 = *(const f32x4*)(in + i);
    f32x4 f1 = *(const f32x4*)(in + i + 4);
    short8 h;
    h[0]=f2bf(f0[0]); h[1]=f2bf(f0[1]); h[2]=f2bf(f0[2]); h[3]=f2bf(f0[3]);
    h[4]=f2bf(f1[0]); h[5]=f2bf(f1[1]); h[6]=f2bf(f1[2]); h[7]=f2bf(f1[3]);
    *(short8*)(out + i) = h;
}

// ---------------------------------------------------------------------------
// Transpose+cast all three QKV weights into Wqkvt [3072][2048]:
//   rows 0-2047 = Wq^T, 2048-2559 = Wk^T, 2560-3071 = Wv^T. K=2048 fixed.
// ---------------------------------------------------------------------------
__global__ __launch_bounds__(256)
void castT3(const float* __restrict__ Wq, const float* __restrict__ Wk,
            const float* __restrict__ Wv, s16* __restrict__ out)
{
    int z = blockIdx.z;
    const float* in; s16* dst; int N;
    if (z == 0)      { in = Wq; dst = out;                        N = 2048; }
    else if (z == 1) { in = Wk; dst = out + (size_t)2048 * 2048;  N = 512; }
    else             { in = Wv; dst = out + (size_t)2560 * 2048;  N = 512; }
    int n0 = blockIdx.x * 32, k0 = blockIdx.y * 32;
    if (n0 >= N) return;

    __shared__ float t[32][33];
    int tx = threadIdx.x & 31, ty = threadIdx.x >> 5;
    for (int i = 0; i < 32; i += 8)
        t[ty + i][tx] = in[(size_t)(k0 + ty + i) * N + n0 + tx];
    __syncthreads();
    for (int i = 0; i < 32; i += 8)
        dst[(size_t)(n0 + ty + i) * 2048 + k0 + tx] = f2bf(t[tx][ty + i]);
}

// ---------------------------------------------------------------------------
// Single-weight transpose+cast: fp32 [2048][2048] -> bf16 [2048][2048]^T.
// ---------------------------------------------------------------------------
__global__ __launch_bounds__(256)
void castT(const float* __restrict__ in, s16* __restrict__ out)
{
    __shared__ float t[32][33];
    int n0 = blockIdx.x * 32, k0 = blockIdx.y * 32;
    int tx = threadIdx.x & 31, ty = threadIdx.x >> 5;
    for (int i = 0; i < 32; i += 8)
        t[ty + i][tx] = in[(size_t)(k0 + ty + i) * 2048 + n0 + tx];
    __syncthreads();
    for (int i = 0; i < 32; i += 8)
        out[(size_t)(n0 + ty + i) * 2048 + k0 + tx] = f2bf(t[tx][ty + i]);
}

// ---------------------------------------------------------------------------
// GEMM v7 "bk64": out = A[M][K] x Bt[N][K]^T + bias.
// = r2's proven m97 2-barrier structure (fastest measured: 92 us QKV) with
// two measured fixes:
//  (a) BK 32 -> 64: 32 K-iterations instead of 64 -> HALF the
//      barrier+vmcnt(0)-drain stalls (the dominant cost of this structure).
//  (b) v4b's LDS geometry, the ONLY one measured conflict-free this session:
//      128-B rows ([128][64] bf16), global 16B-chunk c of row r stored at
//      LDS chunk c^(r&7) (involution; applied by pre-swizzling the GLOBAL
//      source of global_load_lds, rule #21; read offset kc = ((k2*4+fq)^
//      (fr&7))<<4 where kc1 = kc0^64 -- XOR, not add).
//      Empirical: 64-B rows cost 4 conflict-cyc/b128 REGARDLESS of chunk
//      permutation (r2 & v5 both 6.29M); 128-B rows + this swizzle = 0 (v4b).
// Waits: plain __syncthreads(); compiler inserts the correct
// vmcnt/lgkmcnt (m97-verified discipline, race-free).
// LDS 32 KB -> grid-limited 3 blocks/CU.
// MODE 0: QKV split epilogue (n<2048 -> Qb bf16; n<2560 -> Kb bf16;
//         else Vt bf16 transposed).  MODE 2: fp32 out + bias.
// mfma_f32_16x16x32_bf16 layouts (verified m89/m91):
//   A-frag: A[m=lane&15][k=(lane>>4)*8+j]; B-frag: B[k=(lane>>4)*8+j][n=lane&15]
//   C/D:    row=(lane>>4)*4+reg, col=lane&15
// ---------------------------------------------------------------------------
template <int MODE>
__global__ __launch_bounds__(256, 3)
void gemm_bk64(const s16* __restrict__ A, const s16* __restrict__ Bt,
               const float* __restrict__ b0, const float* __restrict__ b1,
               const float* __restrict__ b2,
               void* __restrict__ o0, void* __restrict__ o1, void* __restrict__ o2,
               int M, int N, int K)
{
    __shared__ s16 As[128 * 64];   // [128 rows][64 cols] bf16, 128-B rows
    __shared__ s16 Bs[128 * 64];

    const int tid  = threadIdx.x;
    const int lane = tid & 63, wv = tid >> 6;
    const int m0 = blockIdx.x * 128, n0 = blockIdx.y * 128;
    const int wm = (wv >> 1) * 64, wn = (wv & 1) * 64;
    const int fr = lane & 15, fq = lane >> 4;
    const int NT = K >> 6;

    // ---- staging: instr s covers LDS rows s*32+(tid>>3), chunk tid&7.
    // Pre-swizzled global source chunk = (tid&7) ^ ((tid>>3)&7).
    const int srow = tid >> 3;                       // 0..31
    const int scol = ((tid & 7) ^ (srow & 7)) << 3;  // elements
    const s16* gA[4];
    const s16* gB[4];
    #pragma unroll
    for (int s = 0; s < 4; s++) {
        gA[s] = A  + (size_t)(m0 + s * 32 + srow) * K + scol;
        gB[s] = Bt + (size_t)(n0 + s * 32 + srow) * K + scol;
    }

    // ---- swizzled read offsets: chunk (k2*4+fq)^(fr&7) of row wm+mi*16+fr.
    // r&7 == fr&7 for all frag rows; kc1 = kc0 XOR 64 (bit 6), never add.
    const int kc0 = (fq ^ (fr & 7)) << 4;   // bytes, k2=0
    const int kc1 = kc0 ^ 64;               // k2=1
    const char* aRow = (const char*)As + (wm + fr) * 128;
    const char* bRow = (const char*)Bs + (wn + fr) * 128;

    f32x4 acc[4][4] = {};

    for (int t = 0; t < NT; t++) {
        __syncthreads();   // previous iter's frag reads done -> safe to overwrite
        #pragma unroll
        for (int s = 0; s < 4; s++)
            gload16(gA[s] + t * 64, As + s * 2048 + wv * 512);
        #pragma unroll
        for (int s = 0; s < 4; s++)
            gload16(gB[s] + t * 64, Bs + s * 2048 + wv * 512);
        __syncthreads();   // compiler emits vmcnt(0) drain before this barrier

        short8 af[4][2], bfr[4][2];
        #pragma unroll
        for (int mi = 0; mi < 4; mi++) {
            af[mi][0] = *(const short8*)(aRow + mi * 2048 + kc0);
            af[mi][1] = *(const short8*)(aRow + mi * 2048 + kc1);
        }
        #pragma unroll
        for (int ni = 0; ni < 4; ni++) {
            bfr[ni][0] = *(const short8*)(bRow + ni * 2048 + kc0);
            bfr[ni][1] = *(const short8*)(bRow + ni * 2048 + kc1);
        }

        __builtin_amdgcn_s_setprio(1);
        #pragma unroll
        for (int mi = 0; mi < 4; mi++)
            #pragma unroll
            for (int ni = 0; ni < 4; ni++) {
                acc[mi][ni] = MFMA16(af[mi][0], bfr[ni][0], acc[mi][ni]);
                acc[mi][ni] = MFMA16(af[mi][1], bfr[ni][1], acc[mi][ni]);
            }
        __builtin_amdgcn_s_setprio(0);
    }

    // ---- epilogue ----
    #pragma unroll
    for (int mi = 0; mi < 4; mi++)
        #pragma unroll
        for (int ni = 0; ni < 4; ni++)
            #pragma unroll
            for (int r = 0; r < 4; r++) {
                int m = m0 + wm + mi * 16 + fq * 4 + r;
                int n = n0 + wn + ni * 16 + fr;
                float v = acc[mi][ni][r];
                if (MODE == 0) {
                    if (n < 2048)
                        ((s16*)o0)[(size_t)m * 2048 + n] = f2bf(v + b0[n]);
                    else if (n < 2560)
                        ((s16*)o1)[(size_t)m * 512 + (n - 2048)] = f2bf(v + b1[n - 2048]);
                    else
                        ((s16*)o2)[(size_t)(n - 2560) * 4096 + m] = f2bf(v + b2[n - 2560]);
                } else {
                    ((float*)o0)[(size_t)m * N + n] = v + b0[n];
                }
            }
}

// ---------------------------------------------------------------------------
// Fused RoPE for Q (16 heads) and K (4 heads), in-place, pos 0.
// Blocks [0,16384) -> Qb rows; [16384,20480) -> Kb rows.
// ---------------------------------------------------------------------------
__global__ __launch_bounds__(256)
void rope2_kernel(s16* __restrict__ Qb, s16* __restrict__ Kb)
{
    int bx = blockIdx.x;
    s16* buf; int nheads; int idx;
    if (bx < 16384) { buf = Qb; nheads = 16; idx = bx * 256 + threadIdx.x; }
    else            { buf = Kb; nheads = 4;  idx = (bx - 16384) * 256 + threadIdx.x; }

    int i   = idx & 63;
    int hi  = idx >> 6;
    int h   = hi % nheads;
    int row = hi / nheads;
    int t   = row & 2047;

    float inv_freq = __powf(10000.0f, -(float)i * (1.0f / 64.0f));
    float ang = (float)t * inv_freq;
    float c = cosf(ang);
    float s = sinf(ang);

    size_t base = (size_t)row * ((size_t)nheads * 128) + (size_t)h * 128 + i;
    float x1 = bf2f(buf[base]);
    float x2 = bf2f(buf[base + 64]);
    buf[base]      = f2bf(x1 * c - x2 * s);
    buf[base + 64] = f2bf(x1 * s + x2 * c);
}

// ---------------------------------------------------------------------------
// Flash attention v3 (hybrid), sliding window + sink; both batches (z=b).
// Staging/pipeline = v1 (proven latency-hider): double-buffered K/V in LDS,
// register prefetch, 1 barrier per 32-key chunk, heavy-first dispatch.
// Softmax = v2 (proven correct, 4x less VALU): swapped QK^T (mfma(K,Q)->S^T)
// puts a q-row's 8 chunk scores in-lane; reduce = 7 fmax + 2 shfl; m/l state
// one scalar/lane (log2 domain); defer-max (THR=8) skips most O-rescales;
// P^T->A-frag staged via wave-private Ps (2x ds_write_b64, was 8x b16).
// setprio(1) wrapped around both MFMA clusters (T5, attn-proven).
// Q [4096][2048] bf16; Kb [4096][512]; Vt [512][4096]; At [2][2048][2048].
// ---------------------------------------------------------------------------
__global__ __launch_bounds__(256)
void attn_kernel(const s16* __restrict__ Q, const s16* __restrict__ Kb,
                 const s16* __restrict__ Vt, s16* __restrict__ At)
{
    __shared__ s16 Ks[2][32][136];   // [buf][key][d]
    __shared__ s16 Vs[2][128][40];   // [buf][d][key]
    __shared__ s16 Ps[4][16][40];    // [wave][q][key] P^T staging (wave-private)

    const int b = blockIdx.z;
    const int h = blockIdx.y, g = h >> 2;
    const int t0 = (31 - blockIdx.x) * 64;    // heavy blocks dispatch first
    const int tid = threadIdx.x, lane = tid & 63, wv = tid >> 6;
    const int fr = lane & 15, fq = lane >> 4;
    const int tw = t0 + wv * 16;
    s16* O = At + (size_t)b * 4194304;

    const float SCL2 = 0.12751743f;     // 128^-0.5 * log2(e)  (exp2 domain)
    const float NEG  = -1e9f;
    const float THR2 = 11.541560f;      // 8 * log2(e): defer-max threshold

    // per-thread staging geometry (2 chunks of work for K and V each)
    int kr[2], kc[2], vd[2], vc[2];
    const s16 *gK[2], *gV[2];
    #pragma unroll
    for (int it = 0; it < 2; it++) {
        int idx = it * 2048 + tid * 8;
        kr[it] = idx >> 7;  kc[it] = idx & 127;
        vd[it] = idx >> 5;  vc[it] = idx & 31;
        gK[it] = Kb + (size_t)(b * 2048 + kr[it]) * 512 + g * 128 + kc[it];
        gV[it] = Vt + (size_t)(g * 128 + vd[it]) * 4096 + b * 2048 + vc[it];
    }

    // Q as B-frag: B[k=fq*8+j][n=fr] = Q[tw+fr][d0+fq*8+j]  (whole kernel)
    short8 qf[4];
    {
        const s16* qrow = Q + (size_t)(b * 2048 + tw + fr) * 2048 + h * 128 + fq * 8;
        qf[0] = *(const short8*)(qrow);
        qf[1] = *(const short8*)(qrow + 32);
        qf[2] = *(const short8*)(qrow + 64);
        qf[3] = *(const short8*)(qrow + 96);
    }

    f32x4 Oacc[8] = {};
    float m2 = NEG, l_s = 0.0f;         // softmax state for q = tw + fr
    const int tq = tw + fr;

    int lo = t0 - 512; if (lo < 0) lo = 0;
    const int c0   = lo >> 5;
    const int cend = (t0 + 63) >> 5;
    const int nch  = cend - c0 + 1 + (c0 > 0 ? 1 : 0);

    #define CHUNKBASE(ic) ((((c0) > 0) ? ((ic) == 0 ? 0 : c0 + (ic) - 1) : (ic)) * 32)

    short8 kpre[2], vpre[2];
    {   // prefetch + store chunk 0 into buf 0
        int kb = CHUNKBASE(0);
        #pragma unroll
        for (int it = 0; it < 2; it++) {
            kpre[it] = *(const short8*)(gK[it] + (size_t)kb * 512);
            vpre[it] = *(const short8*)(gV[it] + kb);
        }
        #pragma unroll
        for (int it = 0; it < 2; it++) {
            *(short8*)&Ks[0][kr[it]][kc[it]] = kpre[it];
            *(short8*)&Vs[0][vd[it]][vc[it]] = vpre[it];
        }
    }
    __syncthreads();

    for (int ic = 0; ic < nch; ic++) {
        const int cur = ic & 1;
        const int kbase = CHUNKBASE(ic);
        const bool pre = (ic + 1 < nch);
        if (pre) {
            int kb = CHUNKBASE(ic + 1);
            #pragma unroll
            for (int it = 0; it < 2; it++) {
                kpre[it] = *(const short8*)(gK[it] + (size_t)kb * 512);
                vpre[it] = *(const short8*)(gV[it] + kb);
            }
        }

        // S^T = K Q^T : C row = key (kn*16 + fq*4 + r), col = q (fr).
        f32x4 sc[2] = {{0.f,0.f,0.f,0.f},{0.f,0.f,0.f,0.f}};
        __builtin_amdgcn_s_setprio(1);
        #pragma unroll
        for (int kn = 0; kn < 2; kn++)
            #pragma unroll
            for (int dc = 0; dc < 4; dc++) {
                short8 kf = *(const short8*)&Ks[cur][kn * 16 + fr][dc * 32 + fq * 8];
                sc[kn] = MFMA16(kf, qf[dc], sc[kn]);
            }
        __builtin_amdgcn_s_setprio(0);

        // mask + scale into log2 domain; all 8 values belong to q = tq
        float sv[8];
        #pragma unroll
        for (int kn = 0; kn < 2; kn++)
            #pragma unroll
            for (int r = 0; r < 4; r++) {
                int j = kbase + kn * 16 + fq * 4 + r;
                bool ok = (j <= tq) && ((j >= tq - 512) || (j < 4));
                sv[kn * 4 + r] = ok ? sc[kn][r] * SCL2 : NEG;
            }

        // chunk max for this q-row: in-lane over 8, then across the 4 fq groups
        float cm = fmaxf(sv[0], sv[1]);
        #pragma unroll
        for (int i = 2; i < 8; i++) cm = fmaxf(cm, sv[i]);
        cm = fmaxf(cm, __shfl_xor(cm, 16));
        cm = fmaxf(cm, __shfl_xor(cm, 32));

        // defer-max: only rescale when some row grew by > THR2
        if (__any(cm > m2 + THR2)) {
            float nm    = fmaxf(m2, cm);
            float alpha = exp2f(m2 - nm);
            m2  = nm;
            l_s *= alpha;
            #pragma unroll
            for (int r = 0; r < 4; r++) {
                float ar = __shfl(alpha, (lane & 48) + fq * 4 + r);
                #pragma unroll
                for (int n0 = 0; n0 < 8; n0++) Oacc[n0][r] *= ar;
            }
        }

        float p[8], ps = 0.0f;
        #pragma unroll
        for (int i = 0; i < 8; i++) { p[i] = exp2f(sv[i] - m2); ps += p[i]; }
        ps += __shfl_xor(ps, 16);
        ps += __shfl_xor(ps, 32);
        l_s += ps;

        // P^T (C layout [key][q]) -> Ps[q][key] so pf reads an A-frag
        s16x4 w0, w1;
        #pragma unroll
        for (int r = 0; r < 4; r++) { w0[r] = f2bf(p[r]); w1[r] = f2bf(p[4 + r]); }
        *(s16x4*)&Ps[wv][fr][fq * 4]      = w0;   // keys kn=0: fq*4..fq*4+3
        *(s16x4*)&Ps[wv][fr][16 + fq * 4] = w1;   // keys kn=1
        __threadfence_block();
        short8 pf = *(const short8*)&Ps[wv][fr][fq * 8];  // A[m=q][k=key]

        __builtin_amdgcn_s_setprio(1);
        #pragma unroll
        for (int n0 = 0; n0 < 8; n0++) {
            short8 vf = *(const short8*)&Vs[cur][n0 * 16 + fr][fq * 8];
            Oacc[n0] = MFMA16(pf, vf, Oacc[n0]);
        }
        __builtin_amdgcn_s_setprio(0);

        if (pre) {
            #pragma unroll
            for (int it = 0; it < 2; it++) {
                *(short8*)&Ks[cur ^ 1][kr[it]][kc[it]] = kpre[it];
                *(short8*)&Vs[cur ^ 1][vd[it]][vc[it]] = vpre[it];
            }
            __syncthreads();
        }
    }

    // epilogue: l for Oacc row fq*4+r lives at lane fq*16 + (fq*4+r)
    float linv[4];
    #pragma unroll
    for (int r = 0; r < 4; r++)
        linv[r] = 1.0f / __shfl(l_s, (lane & 48) + fq * 4 + r);
    #pragma unroll
    for (int n0 = 0; n0 < 8; n0++)
        #pragma unroll
        for (int r = 0; r < 4; r++) {
            int t = tw + fq * 4 + r;
            O[(size_t)t * 2048 + h * 128 + n0 * 16 + fr] =
                f2bf(Oacc[n0][r] * linv[r]);
        }
}

// ---------------------------------------------------------------------------
// Launcher (memory map at top of file).
// ---------------------------------------------------------------------------
extern "C" void kernel_launch(void* const* d_in, const int* in_sizes, int n_in,
                              void* d_out, int out_size, void* d_ws, size_t ws_size,
                              hipStream_t stream)
{
    const float* x  = (const float*)d_in[0];
    const float* Wq = (const float*)d_in[1];
    const float* bq = (const float*)d_in[2];
    const float* Wk = (const float*)d_in[3];
    const float* bk = (const float*)d_in[4];
    const float* Wv = (const float*)d_in[5];
    const float* bv = (const float*)d_in[6];
    const float* Wo = (const float*)d_in[7];
    const float* bo = (const float*)d_in[8];
    float* out = (float*)d_out;

    if (ws_size < 33554432) return;

    char* ws = (char*)d_ws;
    s16* xb    = (s16*)(ws + 0);           // [4096][2048] bf16 (16 MB)
    s16* At    = (s16*)(ws + 0);           // [2][2048][2048] bf16 (after xb dies)
    s16* Wqkvt = (s16*)(ws + 16777216);    // [3072][2048] bf16 (12 MB)
    s16* Wot   = (s16*)(ws + 16777216);    // [2048][2048] bf16 (after QKV GEMM)
    s16* Qb    = (s16*)d_out;                              // [4096][2048] bf16
    s16* Kb    = (s16*)((char*)d_out + 16777216);          // [4096][512]  bf16
    s16* Vt    = (s16*)((char*)d_out + 20971520);          // [512][4096]  bf16

    // x -> bf16
    cast_bf16<<<4096, 256, 0, stream>>>(x, xb);

    // QKV weights -> Wqkvt (transposed bf16)
    castT3<<<dim3(64, 64, 3), 256, 0, stream>>>(Wq, Wk, Wv, Wqkvt);

    // fused QKV projection with split epilogue (128^2 tiles, BK=64)
    gemm_bk64<0><<<dim3(32, 24), 256, 0, stream>>>(xb, Wqkvt, bq, bk, bv,
                                                   Qb, Kb, Vt, 4096, 3072, 2048);

    // RoPE on Q and K (one launch)
    rope2_kernel<<<20480, 256, 0, stream>>>(Qb, Kb);

    // O weight (overwrites Wqkvt; stream-ordered after QKV GEMM)
    castT<<<dim3(64, 64), 256, 0, stream>>>(Wo, Wot);

    // attention, both batches (xb dead -> At reuses its space)
    attn_kernel<<<dim3(32, 16, 2), 256, 0, stream>>>(Qb, Kb, Vt, At);

    // output projection: At [4096][2048] x Wot + bo -> out fp32
    gemm_bk64<2><<<dim3(32, 16), 256, 0, stream>>>(At, Wot, bo, nullptr, nullptr,
                                                   out, nullptr, nullptr,
                                                   4096, 2048, 2048);
}

// Round 8
// 305.308 us; speedup vs baseline: 1.6157x; 1.0199x over previous
//
#include <hip/hip_runtime.h>
#include <hip/hip_bf16.h>
#include <cstdint>
#include <cstddef>

// ---------------------------------------------------------------------------
// MaskedSelfAttention: B=2, T=2048, C=2048, NH=16, NG=4, D=128
// sliding window 512 + sink 4, RoPE base 10000, pos 0.
// fp32 I/O; bf16 MFMA internally (fp32 accum).
// Workspace (32 MB):
//   [0,16M):  xb [4096][2048] bf16 -> later At [2][2048][2048] bf16
//   [16,28M): Wqkvt [3072][2048] bf16 -> later Wot [2048][2048] (16-24M)
// d_out scratch (33.5 MB fp32, dead until final O-GEMM):
//   [0,16.78M): Qb [4096][2048] bf16
//   [16.78,20.97M): Kb [4096][512] bf16
//   [20.97,25.17M): Vt [512][4096] bf16
// ---------------------------------------------------------------------------

typedef short s16;
typedef short short8 __attribute__((ext_vector_type(8)));
typedef short s16x4  __attribute__((ext_vector_type(4)));
typedef float f32x4  __attribute__((ext_vector_type(4)));

#define MFMA16(a, b, c) __builtin_amdgcn_mfma_f32_16x16x32_bf16((a), (b), (c), 0, 0, 0)

__device__ __forceinline__ float bf2f(s16 u) {
    union { float f; uint32_t i; } v;
    v.i = ((uint32_t)(uint16_t)u) << 16;
    return v.f;
}
__device__ __forceinline__ s16 f2bf(float f) {
    union { float f; uint32_t i; } v;
    v.f = f;
    uint32_t r = v.i + 0x7FFFu + ((v.i >> 16) & 1u);   // RNE
    return (s16)(r >> 16);
}

// packed f32x2 -> bf16x2 (RNE), single HW instr; no builtin on gfx950 (m240)
__device__ __forceinline__ uint32_t cvtpk_bf16(float lo, float hi) {
    uint32_t r;
    asm("v_cvt_pk_bf16_f32 %0, %1, %2" : "=v"(r) : "v"(lo), "v"(hi));
    return r;
}

// async global->LDS, 16 B per lane; LDS dest = wave-uniform base + lane*16
__device__ __forceinline__ void gload16(const s16* g, s16* l) {
    __builtin_amdgcn_global_load_lds(
        (const __attribute__((address_space(1))) void*)g,
        (__attribute__((address_space(3))) void*)l, 16, 0, 0);
}

// ---------------------------------------------------------------------------
// Elementwise fp32 -> bf16 cast (8 elems/thread).
// ---------------------------------------------------------------------------
__global__ __launch_bounds__(256)
void cast_bf16(const float* __restrict__ in, s16* __restrict__ out)
{
    size_t i = ((size_t)blockIdx.x * 256 + threadIdx.x) * 8;
    f32x4 f0 = *(const f32x4*)(in + i);
    f32x4 f1 = *(const f32x4*)(in + i + 4);
    short8 h;
    h[0]=f2bf(f0[0]); h[1]=f2bf(f0[1]); h[2]=f2bf(f0[2]); h[3]=f2bf(f0[3]);
    h[4]=f2bf(f1[0]); h[5]=f2bf(f1[1]); h[6]=f2bf(f1[2]); h[7]=f2bf(f1[3]);
    *(short8*)(out + i) = h;
}

// ---------------------------------------------------------------------------
// Transpose+cast all three QKV weights into Wqkvt [3072][2048]:
//   rows 0-2047 = Wq^T, 2048-2559 = Wk^T, 2560-3071 = Wv^T. K=2048 fixed.
// ---------------------------------------------------------------------------
__global__ __launch_bounds__(256)
void castT3(const float* __restrict__ Wq, const float* __restrict__ Wk,
            const float* __restrict__ Wv, s16* __restrict__ out)
{
    int z = blockIdx.z;
    const float* in; s16* dst; int N;
    if (z == 0)      { in = Wq; dst = out;                        N = 2048; }
    else if (z == 1) { in = Wk; dst = out + (size_t)2048 * 2048;  N = 512; }
    else             { in = Wv; dst = out + (size_t)2560 * 2048;  N = 512; }
    int n0 = blockIdx.x * 32, k0 = blockIdx.y * 32;
    if (n0 >= N) return;

    __shared__ float t[32][33];
    int tx = threadIdx.x & 31, ty = threadIdx.x >> 5;
    for (int i = 0; i < 32; i += 8)
        t[ty + i][tx] = in[(size_t)(k0 + ty + i) * N + n0 + tx];
    __syncthreads();
    for (int i = 0; i < 32; i += 8)
        dst[(size_t)(n0 + ty + i) * 2048 + k0 + tx] = f2bf(t[tx][ty + i]);
}

// ---------------------------------------------------------------------------
// Single-weight transpose+cast: fp32 [2048][2048] -> bf16 [2048][2048]^T.
// ---------------------------------------------------------------------------
__global__ __launch_bounds__(256)
void castT(const float* __restrict__ in, s16* __restrict__ out)
{
    __shared__ float t[32][33];
    int n0 = blockIdx.x * 32, k0 = blockIdx.y * 32;
    int tx = threadIdx.x & 31, ty = threadIdx.x >> 5;
    for (int i = 0; i < 32; i += 8)
        t[ty + i][tx] = in[(size_t)(k0 + ty + i) * 2048 + n0 + tx];
    __syncthreads();
    for (int i = 0; i < 32; i += 8)
        out[(size_t)(n0 + ty + i) * 2048 + k0 + tx] = f2bf(t[tx][ty + i]);
}

// ---------------------------------------------------------------------------
// GEMM v7 "bk64" (unchanged from r7: QKV+O both < 67 us, conflicts fixed).
// 128x128 tile, BK=64, m97 2-barrier discipline, 128-B LDS rows with
// chunk^=(row&7) swizzle (measured conflict-free, v4b/r7).
// MODE 0: QKV split epilogue; MODE 2: fp32 out + bias.
// ---------------------------------------------------------------------------
template <int MODE>
__global__ __launch_bounds__(256, 3)
void gemm_bk64(const s16* __restrict__ A, const s16* __restrict__ Bt,
               const float* __restrict__ b0, const float* __restrict__ b1,
               const float* __restrict__ b2,
               void* __restrict__ o0, void* __restrict__ o1, void* __restrict__ o2,
               int M, int N, int K)
{
    __shared__ s16 As[128 * 64];   // [128 rows][64 cols] bf16, 128-B rows
    __shared__ s16 Bs[128 * 64];

    const int tid  = threadIdx.x;
    const int lane = tid & 63, wv = tid >> 6;
    const int m0 = blockIdx.x * 128, n0 = blockIdx.y * 128;
    const int wm = (wv >> 1) * 64, wn = (wv & 1) * 64;
    const int fr = lane & 15, fq = lane >> 4;
    const int NT = K >> 6;

    const int srow = tid >> 3;                       // 0..31
    const int scol = ((tid & 7) ^ (srow & 7)) << 3;  // pre-swizzled source
    const s16* gA[4];
    const s16* gB[4];
    #pragma unroll
    for (int s = 0; s < 4; s++) {
        gA[s] = A  + (size_t)(m0 + s * 32 + srow) * K + scol;
        gB[s] = Bt + (size_t)(n0 + s * 32 + srow) * K + scol;
    }

    const int kc0 = (fq ^ (fr & 7)) << 4;   // bytes, k2=0
    const int kc1 = kc0 ^ 64;               // k2=1 (XOR, not add)
    const char* aRow = (const char*)As + (wm + fr) * 128;
    const char* bRow = (const char*)Bs + (wn + fr) * 128;

    f32x4 acc[4][4] = {};

    for (int t = 0; t < NT; t++) {
        __syncthreads();
        #pragma unroll
        for (int s = 0; s < 4; s++)
            gload16(gA[s] + t * 64, As + s * 2048 + wv * 512);
        #pragma unroll
        for (int s = 0; s < 4; s++)
            gload16(gB[s] + t * 64, Bs + s * 2048 + wv * 512);
        __syncthreads();

        short8 af[4][2], bfr[4][2];
        #pragma unroll
        for (int mi = 0; mi < 4; mi++) {
            af[mi][0] = *(const short8*)(aRow + mi * 2048 + kc0);
            af[mi][1] = *(const short8*)(aRow + mi * 2048 + kc1);
        }
        #pragma unroll
        for (int ni = 0; ni < 4; ni++) {
            bfr[ni][0] = *(const short8*)(bRow + ni * 2048 + kc0);
            bfr[ni][1] = *(const short8*)(bRow + ni * 2048 + kc1);
        }

        __builtin_amdgcn_s_setprio(1);
        #pragma unroll
        for (int mi = 0; mi < 4; mi++)
            #pragma unroll
            for (int ni = 0; ni < 4; ni++) {
                acc[mi][ni] = MFMA16(af[mi][0], bfr[ni][0], acc[mi][ni]);
                acc[mi][ni] = MFMA16(af[mi][1], bfr[ni][1], acc[mi][ni]);
            }
        __builtin_amdgcn_s_setprio(0);
    }

    #pragma unroll
    for (int mi = 0; mi < 4; mi++)
        #pragma unroll
        for (int ni = 0; ni < 4; ni++)
            #pragma unroll
            for (int r = 0; r < 4; r++) {
                int m = m0 + wm + mi * 16 + fq * 4 + r;
                int n = n0 + wn + ni * 16 + fr;
                float v = acc[mi][ni][r];
                if (MODE == 0) {
                    if (n < 2048)
                        ((s16*)o0)[(size_t)m * 2048 + n] = f2bf(v + b0[n]);
                    else if (n < 2560)
                        ((s16*)o1)[(size_t)m * 512 + (n - 2048)] = f2bf(v + b1[n - 2048]);
                    else
                        ((s16*)o2)[(size_t)(n - 2560) * 4096 + m] = f2bf(v + b2[n - 2560]);
                } else {
                    ((float*)o0)[(size_t)m * N + n] = v + b0[n];
                }
            }
}

// ---------------------------------------------------------------------------
// Fused RoPE for Q (16 heads) and K (4 heads), in-place, pos 0.
// Blocks [0,16384) -> Qb rows; [16384,20480) -> Kb rows.
// ---------------------------------------------------------------------------
__global__ __launch_bounds__(256)
void rope2_kernel(s16* __restrict__ Qb, s16* __restrict__ Kb)
{
    int bx = blockIdx.x;
    s16* buf; int nheads; int idx;
    if (bx < 16384) { buf = Qb; nheads = 16; idx = bx * 256 + threadIdx.x; }
    else            { buf = Kb; nheads = 4;  idx = (bx - 16384) * 256 + threadIdx.x; }

    int i   = idx & 63;
    int hi  = idx >> 6;
    int h   = hi % nheads;
    int row = hi / nheads;
    int t   = row & 2047;

    float inv_freq = __powf(10000.0f, -(float)i * (1.0f / 64.0f));
    float ang = (float)t * inv_freq;
    float c = cosf(ang);
    float s = sinf(ang);

    size_t base = (size_t)row * ((size_t)nheads * 128) + (size_t)h * 128 + i;
    float x1 = bf2f(buf[base]);
    float x2 = bf2f(buf[base + 64]);
    buf[base]      = f2bf(x1 * c - x2 * s);
    buf[base + 64] = f2bf(x1 * s + x2 * c);
}

// ---------------------------------------------------------------------------
// Flash attention v4: r7 structure + VALU diet (r7 PMC: VALUBusy 44% vs
// MfmaUtil 10% -> softmax VALU-bound).
//  - interior-chunk FAST PATH (wave-uniform: kbase+31<=tw && kbase>=tw+15-512):
//    no mask compares/selects; chunk-max on RAW scores (7 fmax + 1 mul);
//    p = exp2(fma(s_raw, SCL2, -m2)) folds the scale into the exp argument.
//    Boundary/sink chunks take the original masked path.
//  - P->bf16 via v_cvt_pk_bf16_f32 (4 instrs, was 8x ~4-op manual RNE).
// Everything else identical to r7 (double-buffered K/V LDS, reg prefetch,
// swapped QK^T in-lane softmax, defer-max THR=8, setprio on MFMA clusters).
// ---------------------------------------------------------------------------
__global__ __launch_bounds__(256)
void attn_kernel(const s16* __restrict__ Q, const s16* __restrict__ Kb,
                 const s16* __restrict__ Vt, s16* __restrict__ At)
{
    __shared__ s16 Ks[2][32][136];   // [buf][key][d]
    __shared__ s16 Vs[2][128][40];   // [buf][d][key]
    __shared__ s16 Ps[4][16][40];    // [wave][q][key] P^T staging (wave-private)

    const int b = blockIdx.z;
    const int h = blockIdx.y, g = h >> 2;
    const int t0 = (31 - blockIdx.x) * 64;    // heavy blocks dispatch first
    const int tid = threadIdx.x, lane = tid & 63, wv = tid >> 6;
    const int fr = lane & 15, fq = lane >> 4;
    const int tw = t0 + wv * 16;
    s16* O = At + (size_t)b * 4194304;

    const float SCL2 = 0.12751743f;     // 128^-0.5 * log2(e)  (exp2 domain)
    const float NEG  = -1e9f;
    const float THR2 = 11.541560f;      // 8 * log2(e): defer-max threshold

    // per-thread staging geometry (2 chunks of work for K and V each)
    int kr[2], kc[2], vd[2], vc[2];
    const s16 *gK[2], *gV[2];
    #pragma unroll
    for (int it = 0; it < 2; it++) {
        int idx = it * 2048 + tid * 8;
        kr[it] = idx >> 7;  kc[it] = idx & 127;
        vd[it] = idx >> 5;  vc[it] = idx & 31;
        gK[it] = Kb + (size_t)(b * 2048 + kr[it]) * 512 + g * 128 + kc[it];
        gV[it] = Vt + (size_t)(g * 128 + vd[it]) * 4096 + b * 2048 + vc[it];
    }

    // Q as B-frag: B[k=fq*8+j][n=fr] = Q[tw+fr][d0+fq*8+j]  (whole kernel)
    short8 qf[4];
    {
        const s16* qrow = Q + (size_t)(b * 2048 + tw + fr) * 2048 + h * 128 + fq * 8;
        qf[0] = *(const short8*)(qrow);
        qf[1] = *(const short8*)(qrow + 32);
        qf[2] = *(const short8*)(qrow + 64);
        qf[3] = *(const short8*)(qrow + 96);
    }

    f32x4 Oacc[8] = {};
    float m2 = NEG, l_s = 0.0f;         // softmax state for q = tw + fr
    const int tq = tw + fr;

    int lo = t0 - 512; if (lo < 0) lo = 0;
    const int c0   = lo >> 5;
    const int cend = (t0 + 63) >> 5;
    const int nch  = cend - c0 + 1 + (c0 > 0 ? 1 : 0);

    #define CHUNKBASE(ic) ((((c0) > 0) ? ((ic) == 0 ? 0 : c0 + (ic) - 1) : (ic)) * 32)

    short8 kpre[2], vpre[2];
    {   // prefetch + store chunk 0 into buf 0
        int kb = CHUNKBASE(0);
        #pragma unroll
        for (int it = 0; it < 2; it++) {
            kpre[it] = *(const short8*)(gK[it] + (size_t)kb * 512);
            vpre[it] = *(const short8*)(gV[it] + kb);
        }
        #pragma unroll
        for (int it = 0; it < 2; it++) {
            *(short8*)&Ks[0][kr[it]][kc[it]] = kpre[it];
            *(short8*)&Vs[0][vd[it]][vc[it]] = vpre[it];
        }
    }
    __syncthreads();

    for (int ic = 0; ic < nch; ic++) {
        const int cur = ic & 1;
        const int kbase = CHUNKBASE(ic);
        const bool pre = (ic + 1 < nch);
        if (pre) {
            int kb = CHUNKBASE(ic + 1);
            #pragma unroll
            for (int it = 0; it < 2; it++) {
                kpre[it] = *(const short8*)(gK[it] + (size_t)kb * 512);
                vpre[it] = *(const short8*)(gV[it] + kb);
            }
        }

        // S^T = K Q^T : C row = key (kn*16 + fq*4 + r), col = q (fr).
        f32x4 sc[2] = {{0.f,0.f,0.f,0.f},{0.f,0.f,0.f,0.f}};
        __builtin_amdgcn_s_setprio(1);
        #pragma unroll
        for (int kn = 0; kn < 2; kn++)
            #pragma unroll
            for (int dc = 0; dc < 4; dc++) {
                short8 kf = *(const short8*)&Ks[cur][kn * 16 + fr][dc * 32 + fq * 8];
                sc[kn] = MFMA16(kf, qf[dc], sc[kn]);
            }
        __builtin_amdgcn_s_setprio(0);

        // fast path: chunk valid for ALL 16 q-rows of this wave (wave-uniform)
        const bool fast = (kbase + 31 <= tw) && (kbase >= tw + 15 - 512);

        float sv[8], cm;
        if (fast) {
            // raw-domain max; scale folded once
            #pragma unroll
            for (int i = 0; i < 4; i++) { sv[i] = sc[0][i]; sv[4 + i] = sc[1][i]; }
            float a0 = fmaxf(sv[0], sv[1]), a1 = fmaxf(sv[2], sv[3]);
            float a2 = fmaxf(sv[4], sv[5]), a3 = fmaxf(sv[6], sv[7]);
            cm = fmaxf(fmaxf(a0, a1), fmaxf(a2, a3)) * SCL2;
        } else {
            #pragma unroll
            for (int kn = 0; kn < 2; kn++)
                #pragma unroll
                for (int r = 0; r < 4; r++) {
                    int j = kbase + kn * 16 + fq * 4 + r;
                    bool ok = (j <= tq) && ((j >= tq - 512) || (j < 4));
                    sv[kn * 4 + r] = ok ? sc[kn][r] * SCL2 : NEG;
                }
            cm = fmaxf(sv[0], sv[1]);
            #pragma unroll
            for (int i = 2; i < 8; i++) cm = fmaxf(cm, sv[i]);
        }
        cm = fmaxf(cm, __shfl_xor(cm, 16));
        cm = fmaxf(cm, __shfl_xor(cm, 32));

        // defer-max: only rescale when some row grew by > THR2
        if (__any(cm > m2 + THR2)) {
            float nm    = fmaxf(m2, cm);
            float alpha = exp2f(m2 - nm);
            m2  = nm;
            l_s *= alpha;
            #pragma unroll
            for (int r = 0; r < 4; r++) {
                float ar = __shfl(alpha, (lane & 48) + fq * 4 + r);
                #pragma unroll
                for (int n0 = 0; n0 < 8; n0++) Oacc[n0][r] *= ar;
            }
        }

        float p[8], ps = 0.0f;
        if (fast) {
            const float nm2 = -m2;
            #pragma unroll
            for (int i = 0; i < 8; i++) { p[i] = exp2f(fmaf(sv[i], SCL2, nm2)); ps += p[i]; }
        } else {
            #pragma unroll
            for (int i = 0; i < 8; i++) { p[i] = exp2f(sv[i] - m2); ps += p[i]; }
        }
        ps += __shfl_xor(ps, 16);
        ps += __shfl_xor(ps, 32);
        l_s += ps;

        // P^T (C layout [key][q]) -> Ps[q][key]; packed bf16 conversion
        union { s16x4 v; uint32_t u[2]; } w0, w1;
        w0.u[0] = cvtpk_bf16(p[0], p[1]);
        w0.u[1] = cvtpk_bf16(p[2], p[3]);
        w1.u[0] = cvtpk_bf16(p[4], p[5]);
        w1.u[1] = cvtpk_bf16(p[6], p[7]);
        *(s16x4*)&Ps[wv][fr][fq * 4]      = w0.v;   // keys kn=0: fq*4..fq*4+3
        *(s16x4*)&Ps[wv][fr][16 + fq * 4] = w1.v;   // keys kn=1
        __threadfence_block();
        short8 pf = *(const short8*)&Ps[wv][fr][fq * 8];  // A[m=q][k=key]

        __builtin_amdgcn_s_setprio(1);
        #pragma unroll
        for (int n0 = 0; n0 < 8; n0++) {
            short8 vf = *(const short8*)&Vs[cur][n0 * 16 + fr][fq * 8];
            Oacc[n0] = MFMA16(pf, vf, Oacc[n0]);
        }
        __builtin_amdgcn_s_setprio(0);

        if (pre) {
            #pragma unroll
            for (int it = 0; it < 2; it++) {
                *(short8*)&Ks[cur ^ 1][kr[it]][kc[it]] = kpre[it];
                *(short8*)&Vs[cur ^ 1][vd[it]][vc[it]] = vpre[it];
            }
            __syncthreads();
        }
    }

    // epilogue: l for Oacc row fq*4+r lives at lane fq*16 + (fq*4+r)
    float linv[4];
    #pragma unroll
    for (int r = 0; r < 4; r++)
        linv[r] = 1.0f / __shfl(l_s, (lane & 48) + fq * 4 + r);
    #pragma unroll
    for (int n0 = 0; n0 < 8; n0++)
        #pragma unroll
        for (int r = 0; r < 4; r++) {
            int t = tw + fq * 4 + r;
            O[(size_t)t * 2048 + h * 128 + n0 * 16 + fr] =
                f2bf(Oacc[n0][r] * linv[r]);
        }
}

// ---------------------------------------------------------------------------
// Launcher (memory map at top of file).
// ---------------------------------------------------------------------------
extern "C" void kernel_launch(void* const* d_in, const int* in_sizes, int n_in,
                              void* d_out, int out_size, void* d_ws, size_t ws_size,
                              hipStream_t stream)
{
    const float* x  = (const float*)d_in[0];
    const float* Wq = (const float*)d_in[1];
    const float* bq = (const float*)d_in[2];
    const float* Wk = (const float*)d_in[3];
    const float* bk = (const float*)d_in[4];
    const float* Wv = (const float*)d_in[5];
    const float* bv = (const float*)d_in[6];
    const float* Wo = (const float*)d_in[7];
    const float* bo = (const float*)d_in[8];
    float* out = (float*)d_out;

    if (ws_size < 33554432) return;

    char* ws = (char*)d_ws;
    s16* xb    = (s16*)(ws + 0);           // [4096][2048] bf16 (16 MB)
    s16* At    = (s16*)(ws + 0);           // [2][2048][2048] bf16 (after xb dies)
    s16* Wqkvt = (s16*)(ws + 16777216);    // [3072][2048] bf16 (12 MB)
    s16* Wot   = (s16*)(ws + 16777216);    // [2048][2048] bf16 (after QKV GEMM)
    s16* Qb    = (s16*)d_out;                              // [4096][2048] bf16
    s16* Kb    = (s16*)((char*)d_out + 16777216);          // [4096][512]  bf16
    s16* Vt    = (s16*)((char*)d_out + 20971520);          // [512][4096]  bf16

    // x -> bf16
    cast_bf16<<<4096, 256, 0, stream>>>(x, xb);

    // QKV weights -> Wqkvt (transposed bf16)
    castT3<<<dim3(64, 64, 3), 256, 0, stream>>>(Wq, Wk, Wv, Wqkvt);

    // fused QKV projection with split epilogue (128^2 tiles, BK=64)
    gemm_bk64<0><<<dim3(32, 24), 256, 0, stream>>>(xb, Wqkvt, bq, bk, bv,
                                                   Qb, Kb, Vt, 4096, 3072, 2048);

    // RoPE on Q and K (one launch)
    rope2_kernel<<<20480, 256, 0, stream>>>(Qb, Kb);

    // O weight (overwrites Wqkvt; stream-ordered after QKV GEMM)
    castT<<<dim3(64, 64), 256, 0, stream>>>(Wo, Wot);

    // attention, both batches (xb dead -> At reuses its space)
    attn_kernel<<<dim3(32, 16, 2), 256, 0, stream>>>(Qb, Kb, Vt, At);

    // output projection: At [4096][2048] x Wot + bo -> out fp32
    gemm_bk64<2><<<dim3(32, 16), 256, 0, stream>>>(At, Wot, bo, nullptr, nullptr,
                                                   out, nullptr, nullptr,
                                                   4096, 2048, 2048);
}

// Round 9
// 290.048 us; speedup vs baseline: 1.7007x; 1.0526x over previous
//
#include <hip/hip_runtime.h>
#include <hip/hip_bf16.h>
#include <cstdint>
#include <cstddef>

// ---------------------------------------------------------------------------
// MaskedSelfAttention: B=2, T=2048, C=2048, NH=16, NG=4, D=128
// sliding window 512 + sink 4, RoPE base 10000, pos 0.
// fp32 I/O; bf16 MFMA internally (fp32 accum).
// Workspace (32 MB):
//   [0,16M):  xb [4096][2048] bf16 -> later At [2][2048][2048] bf16
//   [16,28M): Wqkvt [3072][2048] bf16 -> later Wot [2048][2048] (16-24M)
//   [28,29M): RoPE table float2[2048][64] (cos,sin)
// d_out scratch (33.5 MB fp32, dead until final O-GEMM):
//   [0,16.78M): Qb [4096][2048] bf16
//   [16.78,20.97M): Kb [4096][512] bf16
//   [20.97,25.17M): Vt [512][4096] bf16
// ---------------------------------------------------------------------------

typedef short s16;
typedef short short8 __attribute__((ext_vector_type(8)));
typedef short s16x4  __attribute__((ext_vector_type(4)));
typedef float f32x4  __attribute__((ext_vector_type(4)));

#define MFMA16(a, b, c) __builtin_amdgcn_mfma_f32_16x16x32_bf16((a), (b), (c), 0, 0, 0)

__device__ __forceinline__ float bf2f(s16 u) {
    union { float f; uint32_t i; } v;
    v.i = ((uint32_t)(uint16_t)u) << 16;
    return v.f;
}
__device__ __forceinline__ s16 f2bf(float f) {
    union { float f; uint32_t i; } v;
    v.f = f;
    uint32_t r = v.i + 0x7FFFu + ((v.i >> 16) & 1u);   // RNE
    return (s16)(r >> 16);
}

// packed f32x2 -> bf16x2 (RNE), single HW instr; no builtin on gfx950 (m240)
__device__ __forceinline__ uint32_t cvtpk_bf16(float lo, float hi) {
    uint32_t r;
    asm("v_cvt_pk_bf16_f32 %0, %1, %2" : "=v"(r) : "v"(lo), "v"(hi));
    return r;
}

// async global->LDS, 16 B per lane; LDS dest = wave-uniform base + lane*16
__device__ __forceinline__ void gload16(const s16* g, s16* l) {
    __builtin_amdgcn_global_load_lds(
        (const __attribute__((address_space(1))) void*)g,
        (__attribute__((address_space(3))) void*)l, 16, 0, 0);
}

// ---------------------------------------------------------------------------
// prep: fused (z=0..2) QKV weight transpose+cast, (z=3) RoPE table,
// (z=4) x fp32->bf16 cast.  One launch instead of two (+ rope precompute).
// ---------------------------------------------------------------------------
__global__ __launch_bounds__(256)
void prep(const float* __restrict__ Wq, const float* __restrict__ Wk,
          const float* __restrict__ Wv, const float* __restrict__ x,
          s16* __restrict__ wout, float2* __restrict__ tab,
          s16* __restrict__ xb)
{
    int z = blockIdx.z;
    if (z == 4) {        // x cast: 4096 blocks x 256 thr x 8 elems
        size_t i = ((size_t)(blockIdx.x * 64 + blockIdx.y) * 256 + threadIdx.x) * 8;
        f32x4 f0 = *(const f32x4*)(x + i);
        f32x4 f1 = *(const f32x4*)(x + i + 4);
        short8 h;
        h[0]=f2bf(f0[0]); h[1]=f2bf(f0[1]); h[2]=f2bf(f0[2]); h[3]=f2bf(f0[3]);
        h[4]=f2bf(f1[0]); h[5]=f2bf(f1[1]); h[6]=f2bf(f1[2]); h[7]=f2bf(f1[3]);
        *(short8*)(xb + i) = h;
        return;
    }
    if (z == 3) {        // RoPE table: tab[t*64+i] = (cos, sin)(t * 10000^(-i/64))
        if (blockIdx.x >= 8) return;
        int e = (blockIdx.x * 64 + blockIdx.y) * 256 + threadIdx.x;
        int t = e >> 6, i = e & 63;
        float inv = __powf(10000.0f, -(float)i * (1.0f / 64.0f));
        float ang = (float)t * inv;
        tab[e] = make_float2(cosf(ang), sinf(ang));
        return;
    }
    const float* in; s16* dst; int N;
    if (z == 0)      { in = Wq; dst = wout;                        N = 2048; }
    else if (z == 1) { in = Wk; dst = wout + (size_t)2048 * 2048;  N = 512; }
    else             { in = Wv; dst = wout + (size_t)2560 * 2048;  N = 512; }
    int n0 = blockIdx.x * 32, k0 = blockIdx.y * 32;
    if (n0 >= N) return;

    __shared__ float t[32][33];
    int tx = threadIdx.x & 31, ty = threadIdx.x >> 5;
    for (int i = 0; i < 32; i += 8)
        t[ty + i][tx] = in[(size_t)(k0 + ty + i) * N + n0 + tx];
    __syncthreads();
    for (int i = 0; i < 32; i += 8)
        dst[(size_t)(n0 + ty + i) * 2048 + k0 + tx] = f2bf(t[tx][ty + i]);
}

// ---------------------------------------------------------------------------
// Single-weight transpose+cast: fp32 [2048][2048] -> bf16 [2048][2048]^T.
// (Wo; separate launch because Wot overwrites Wqkvt after the QKV GEMM.)
// ---------------------------------------------------------------------------
__global__ __launch_bounds__(256)
void castT(const float* __restrict__ in, s16* __restrict__ out)
{
    __shared__ float t[32][33];
    int n0 = blockIdx.x * 32, k0 = blockIdx.y * 32;
    int tx = threadIdx.x & 31, ty = threadIdx.x >> 5;
    for (int i = 0; i < 32; i += 8)
        t[ty + i][tx] = in[(size_t)(k0 + ty + i) * 2048 + n0 + tx];
    __syncthreads();
    for (int i = 0; i < 32; i += 8)
        out[(size_t)(n0 + ty + i) * 2048 + k0 + tx] = f2bf(t[tx][ty + i]);
}

// ---------------------------------------------------------------------------
// GEMM "bk64" (r7 structure, unchanged main loop: 128x128 tile, BK=64,
// m97 2-barrier discipline, 128-B LDS rows with chunk^=(row&7) swizzle --
// measured conflict-free).
// MODE 0: QKV split epilogue WITH FUSED RoPE for n<2560 (Q and K heads):
//   tile n-range = one head (128 cols). Odd waves (cols 64-127 = i+64 half)
//   stage acc+bias to As/Bs-as-fp32 [64][64]; barrier; even waves rotate
//   (table lookup, ws+28M) and write BOTH halves bf16. V cols (n>=2560)
//   take the normal transposed epilogue. Rotation is pre-bf16-rounding
//   (slightly more accurate than the old separate rope pass).
// MODE 2: fp32 out + bias.
// mfma_f32_16x16x32_bf16 layouts (verified m89/m91):
//   A-frag: A[m=lane&15][k=(lane>>4)*8+j]; B-frag: B[k=(lane>>4)*8+j][n=lane&15]
//   C/D:    row=(lane>>4)*4+reg, col=lane&15
// ---------------------------------------------------------------------------
template <int MODE>
__global__ __launch_bounds__(256, 3)
void gemm_bk64(const s16* __restrict__ A, const s16* __restrict__ Bt,
               const float* __restrict__ b0, const float* __restrict__ b1,
               const float* __restrict__ b2, const float2* __restrict__ tab,
               void* __restrict__ o0, void* __restrict__ o1, void* __restrict__ o2,
               int M, int N, int K)
{
    __shared__ s16 As[128 * 64];   // [128 rows][64 cols] bf16, 128-B rows
    __shared__ s16 Bs[128 * 64];

    const int tid  = threadIdx.x;
    const int lane = tid & 63, wv = tid >> 6;
    const int m0 = blockIdx.x * 128, n0 = blockIdx.y * 128;
    const int wm = (wv >> 1) * 64, wn = (wv & 1) * 64;
    const int fr = lane & 15, fq = lane >> 4;
    const int NT = K >> 6;

    const int srow = tid >> 3;                       // 0..31
    const int scol = ((tid & 7) ^ (srow & 7)) << 3;  // pre-swizzled source
    const s16* gA[4];
    const s16* gB[4];
    #pragma unroll
    for (int s = 0; s < 4; s++) {
        gA[s] = A  + (size_t)(m0 + s * 32 + srow) * K + scol;
        gB[s] = Bt + (size_t)(n0 + s * 32 + srow) * K + scol;
    }

    const int kc0 = (fq ^ (fr & 7)) << 4;   // bytes, k2=0
    const int kc1 = kc0 ^ 64;               // k2=1 (XOR, not add)
    const char* aRow = (const char*)As + (wm + fr) * 128;
    const char* bRow = (const char*)Bs + (wn + fr) * 128;

    f32x4 acc[4][4] = {};

    for (int t = 0; t < NT; t++) {
        __syncthreads();
        #pragma unroll
        for (int s = 0; s < 4; s++)
            gload16(gA[s] + t * 64, As + s * 2048 + wv * 512);
        #pragma unroll
        for (int s = 0; s < 4; s++)
            gload16(gB[s] + t * 64, Bs + s * 2048 + wv * 512);
        __syncthreads();

        short8 af[4][2], bfr[4][2];
        #pragma unroll
        for (int mi = 0; mi < 4; mi++) {
            af[mi][0] = *(const short8*)(aRow + mi * 2048 + kc0);
            af[mi][1] = *(const short8*)(aRow + mi * 2048 + kc1);
        }
        #pragma unroll
        for (int ni = 0; ni < 4; ni++) {
            bfr[ni][0] = *(const short8*)(bRow + ni * 2048 + kc0);
            bfr[ni][1] = *(const short8*)(bRow + ni * 2048 + kc1);
        }

        __builtin_amdgcn_s_setprio(1);
        #pragma unroll
        for (int mi = 0; mi < 4; mi++)
            #pragma unroll
            for (int ni = 0; ni < 4; ni++) {
                acc[mi][ni] = MFMA16(af[mi][0], bfr[ni][0], acc[mi][ni]);
                acc[mi][ni] = MFMA16(af[mi][1], bfr[ni][1], acc[mi][ni]);
            }
        __builtin_amdgcn_s_setprio(0);
    }

    // ---- epilogue ----
    if (MODE == 0 && n0 < 2560) {
        // fused RoPE: this tile is one head; pair (i, i+64) spans the
        // wn=0 / wn=64 wave halves -> exchange odd half via LDS (fp32).
        const bool qreg = (n0 < 2048);
        float* xch = (float*)(wm ? Bs : As);    // [64][64] fp32 per wm-half
        __syncthreads();                        // main-loop LDS reads done
        if (wn) {       // odd waves: stage acc+bias
            #pragma unroll
            for (int mi = 0; mi < 4; mi++)
                #pragma unroll
                for (int ni = 0; ni < 4; ni++)
                    #pragma unroll
                    for (int r = 0; r < 4; r++) {
                        int n = n0 + 64 + ni * 16 + fr;
                        float bv = qreg ? b0[n] : b1[n - 2048];
                        xch[(mi * 16 + fq * 4 + r) * 64 + ni * 16 + fr] =
                            acc[mi][ni][r] + bv;
                    }
        }
        __syncthreads();
        if (!wn) {      // even waves: rotate + write both halves
            #pragma unroll
            for (int mi = 0; mi < 4; mi++)
                #pragma unroll
                for (int ni = 0; ni < 4; ni++)
                    #pragma unroll
                    for (int r = 0; r < 4; r++) {
                        int m = m0 + wm + mi * 16 + fq * 4 + r;
                        int n = n0 + ni * 16 + fr;
                        int i = ni * 16 + fr;          // 0..63
                        float bv = qreg ? b0[n] : b1[n - 2048];
                        float x1 = acc[mi][ni][r] + bv;
                        float x2 = xch[(mi * 16 + fq * 4 + r) * 64 + i];
                        float2 cs = tab[(size_t)(m & 2047) * 64 + i];
                        float ro1 = x1 * cs.x - x2 * cs.y;
                        float ro2 = x1 * cs.y + x2 * cs.x;
                        if (qreg) {
                            s16* q = (s16*)o0;
                            q[(size_t)m * 2048 + n]      = f2bf(ro1);
                            q[(size_t)m * 2048 + n + 64] = f2bf(ro2);
                        } else {
                            s16* k = (s16*)o1;
                            k[(size_t)m * 512 + (n - 2048)]      = f2bf(ro1);
                            k[(size_t)m * 512 + (n - 2048) + 64] = f2bf(ro2);
                        }
                    }
        }
        return;
    }

    #pragma unroll
    for (int mi = 0; mi < 4; mi++)
        #pragma unroll
        for (int ni = 0; ni < 4; ni++)
            #pragma unroll
            for (int r = 0; r < 4; r++) {
                int m = m0 + wm + mi * 16 + fq * 4 + r;
                int n = n0 + wn + ni * 16 + fr;
                float v = acc[mi][ni][r];
                if (MODE == 0) {
                    // only V region (n >= 2560) reaches here in MODE 0
                    ((s16*)o2)[(size_t)(n - 2560) * 4096 + m] = f2bf(v + b2[n - 2560]);
                } else {
                    ((float*)o0)[(size_t)m * N + n] = v + b0[n];
                }
            }
}

// ---------------------------------------------------------------------------
// Flash attention v5: r8 structure with ALL LDS buffers rebuilt in the
// empirically-proven conflict-free geometry (128-B row pitch, 16-B chunks,
// chunk ^= (row&7); every 8-lane issue group covers 8 distinct chunks --
// the same pattern that measured 0 conflicts in the GEMM, vs ~4 extra
// cycles/access for every other geometry tried this session).
//   Ks[buf][64][64]: (key,d) -> row = key + 32*(d>>6), chunk=(d>>3)&7 ^ key&7
//   Vs[buf][64][64]: (d,key) -> row = d>>1, col = (d&1)*32+key, ^((d>>1)&7)
//   Ps[wv][8][64]:   (q,key) -> row = q>>1,  col = (q&1)*32+key, ^((q>>1)&7)
// (write/read mappings hand-verified on 3 end-to-end examples.)
// Rest identical to r8: double-buffered K/V, reg prefetch, swapped QK^T
// in-lane softmax, interior fast path, defer-max, cvt_pk, setprio.
// ---------------------------------------------------------------------------
__global__ __launch_bounds__(256)
void attn_kernel(const s16* __restrict__ Q, const s16* __restrict__ Kb,
                 const s16* __restrict__ Vt, s16* __restrict__ At)
{
    __shared__ s16 Ks[2][64][64];
    __shared__ s16 Vs[2][64][64];
    __shared__ s16 Ps[4][8][64];

    const int b = blockIdx.z;
    const int h = blockIdx.y, g = h >> 2;
    const int t0 = (31 - blockIdx.x) * 64;    // heavy blocks dispatch first
    const int tid = threadIdx.x, lane = tid & 63, wv = tid >> 6;
    const int fr = lane & 15, fq = lane >> 4;
    const int tw = t0 + wv * 16;
    s16* O = At + (size_t)b * 4194304;

    const float SCL2 = 0.12751743f;     // 128^-0.5 * log2(e)  (exp2 domain)
    const float NEG  = -1e9f;
    const float THR2 = 11.541560f;      // 8 * log2(e): defer-max threshold

    // staging geometry: thread covers 8 elems of the K tile (key,d layout)
    // and 8 elems of the V tile (d,key layout) per 'it'.
    int kwoff[2], vwoff[2];
    const s16 *gK[2], *gV[2];
    #pragma unroll
    for (int it = 0; it < 2; it++) {
        int idx  = it * 2048 + tid * 8;
        int key  = idx >> 7, d = idx & 127;          // K tile coords
        int krow = key + 32 * (d >> 6);
        kwoff[it] = krow * 128 + ((((d >> 3) & 7) ^ (key & 7)) << 4);
        int vd   = idx >> 5, vkey = idx & 31;        // V tile coords
        int vrow = vd >> 1;
        vwoff[it] = vrow * 128 +
                    (((((vd & 1) * 4 + (vkey >> 3)) ^ (vrow & 7))) << 4);
        gK[it] = Kb + (size_t)(b * 2048 + key) * 512 + g * 128 + d;
        gV[it] = Vt + (size_t)(g * 128 + vd) * 4096 + b * 2048 + vkey;
    }

    // per-lane read constants
    const int kc0 = (fq ^ (fr & 7)) << 4;
    const int kc1 = kc0 ^ 64;
    const int vc0 = ((((fr & 1) * 4 + fq) ^ ((fr >> 1) & 7)) << 4);
    const int pw0 = (fr >> 1) * 128 +
                    ((((fr & 1) * 4 + (fq >> 1)) ^ ((fr >> 1) & 7)) << 4) +
                    (fq & 1) * 8;
    const int pw1 = pw0 ^ 32;
    char* psbase = (char*)&Ps[wv][0][0];

    // Q as B-frag: B[k=fq*8+j][n=fr] = Q[tw+fr][d0+fq*8+j]  (whole kernel)
    short8 qf[4];
    {
        const s16* qrow = Q + (size_t)(b * 2048 + tw + fr) * 2048 + h * 128 + fq * 8;
        qf[0] = *(const short8*)(qrow);
        qf[1] = *(const short8*)(qrow + 32);
        qf[2] = *(const short8*)(qrow + 64);
        qf[3] = *(const short8*)(qrow + 96);
    }

    f32x4 Oacc[8] = {};
    float m2 = NEG, l_s = 0.0f;         // softmax state for q = tw + fr
    const int tq = tw + fr;

    int lo = t0 - 512; if (lo < 0) lo = 0;
    const int c0   = lo >> 5;
    const int cend = (t0 + 63) >> 5;
    const int nch  = cend - c0 + 1 + (c0 > 0 ? 1 : 0);

    #define CHUNKBASE(ic) ((((c0) > 0) ? ((ic) == 0 ? 0 : c0 + (ic) - 1) : (ic)) * 32)

    short8 kpre[2], vpre[2];
    {   // prefetch + store chunk 0 into buf 0
        int kb = CHUNKBASE(0);
        #pragma unroll
        for (int it = 0; it < 2; it++) {
            kpre[it] = *(const short8*)(gK[it] + (size_t)kb * 512);
            vpre[it] = *(const short8*)(gV[it] + kb);
        }
        #pragma unroll
        for (int it = 0; it < 2; it++) {
            *(short8*)((char*)&Ks[0][0][0] + kwoff[it]) = kpre[it];
            *(short8*)((char*)&Vs[0][0][0] + vwoff[it]) = vpre[it];
        }
    }
    __syncthreads();

    for (int ic = 0; ic < nch; ic++) {
        const int cur = ic & 1;
        const int kbase = CHUNKBASE(ic);
        const bool pre = (ic + 1 < nch);
        if (pre) {
            int kb = CHUNKBASE(ic + 1);
            #pragma unroll
            for (int it = 0; it < 2; it++) {
                kpre[it] = *(const short8*)(gK[it] + (size_t)kb * 512);
                vpre[it] = *(const short8*)(gV[it] + kb);
            }
        }

        // S^T = K Q^T : C row = key (kn*16 + fq*4 + r), col = q (fr).
        const char* kbl = (const char*)&Ks[cur][0][0] + fr * 128;
        f32x4 sc[2] = {{0.f,0.f,0.f,0.f},{0.f,0.f,0.f,0.f}};
        __builtin_amdgcn_s_setprio(1);
        #pragma unroll
        for (int kn = 0; kn < 2; kn++)
            #pragma unroll
            for (int dc = 0; dc < 4; dc++) {
                short8 kf = *(const short8*)(kbl + kn * 2048 + (dc >> 1) * 4096
                                             + ((dc & 1) ? kc1 : kc0));
                sc[kn] = MFMA16(kf, qf[dc], sc[kn]);
            }
        __builtin_amdgcn_s_setprio(0);

        // fast path: chunk valid for ALL 16 q-rows of this wave (wave-uniform)
        const bool fast = (kbase + 31 <= tw) && (kbase >= tw + 15 - 512);

        float sv[8], cm;
        if (fast) {
            #pragma unroll
            for (int i = 0; i < 4; i++) { sv[i] = sc[0][i]; sv[4 + i] = sc[1][i]; }
            float a0 = fmaxf(sv[0], sv[1]), a1 = fmaxf(sv[2], sv[3]);
            float a2 = fmaxf(sv[4], sv[5]), a3 = fmaxf(sv[6], sv[7]);
            cm = fmaxf(fmaxf(a0, a1), fmaxf(a2, a3)) * SCL2;
        } else {
            #pragma unroll
            for (int kn = 0; kn < 2; kn++)
                #pragma unroll
                for (int r = 0; r < 4; r++) {
                    int j = kbase + kn * 16 + fq * 4 + r;
                    bool ok = (j <= tq) && ((j >= tq - 512) || (j < 4));
                    sv[kn * 4 + r] = ok ? sc[kn][r] * SCL2 : NEG;
                }
            cm = fmaxf(sv[0], sv[1]);
            #pragma unroll
            for (int i = 2; i < 8; i++) cm = fmaxf(cm, sv[i]);
        }
        cm = fmaxf(cm, __shfl_xor(cm, 16));
        cm = fmaxf(cm, __shfl_xor(cm, 32));

        // defer-max: only rescale when some row grew by > THR2
        if (__any(cm > m2 + THR2)) {
            float nm    = fmaxf(m2, cm);
            float alpha = exp2f(m2 - nm);
            m2  = nm;
            l_s *= alpha;
            #pragma unroll
            for (int r = 0; r < 4; r++) {
                float ar = __shfl(alpha, (lane & 48) + fq * 4 + r);
                #pragma unroll
                for (int n0 = 0; n0 < 8; n0++) Oacc[n0][r] *= ar;
            }
        }

        float p[8], ps = 0.0f;
        if (fast) {
            const float nm2 = -m2;
            #pragma unroll
            for (int i = 0; i < 8; i++) { p[i] = exp2f(fmaf(sv[i], SCL2, nm2)); ps += p[i]; }
        } else {
            #pragma unroll
            for (int i = 0; i < 8; i++) { p[i] = exp2f(sv[i] - m2); ps += p[i]; }
        }
        ps += __shfl_xor(ps, 16);
        ps += __shfl_xor(ps, 32);
        l_s += ps;

        // P^T (C layout [key][q]) -> Ps[q][key] swizzled; packed bf16
        union { s16x4 v; uint32_t u[2]; } w0, w1;
        w0.u[0] = cvtpk_bf16(p[0], p[1]);
        w0.u[1] = cvtpk_bf16(p[2], p[3]);
        w1.u[0] = cvtpk_bf16(p[4], p[5]);
        w1.u[1] = cvtpk_bf16(p[6], p[7]);
        *(s16x4*)(psbase + pw0) = w0.v;   // keys kn=0
        *(s16x4*)(psbase + pw1) = w1.v;   // keys kn=1
        __threadfence_block();
        short8 pf = *(const short8*)(psbase + (fr >> 1) * 128 + vc0);

        __builtin_amdgcn_s_setprio(1);
        const char* vbl = (const char*)&Vs[cur][0][0] + (fr >> 1) * 128 + vc0;
        #pragma unroll
        for (int n0 = 0; n0 < 8; n0++) {
            short8 vf = *(const short8*)(vbl + n0 * 1024);
            Oacc[n0] = MFMA16(pf, vf, Oacc[n0]);
        }
        __builtin_amdgcn_s_setprio(0);

        if (pre) {
            #pragma unroll
            for (int it = 0; it < 2; it++) {
                *(short8*)((char*)&Ks[cur ^ 1][0][0] + kwoff[it]) = kpre[it];
                *(short8*)((char*)&Vs[cur ^ 1][0][0] + vwoff[it]) = vpre[it];
            }
            __syncthreads();
        }
    }

    // epilogue: l for Oacc row fq*4+r lives at lane fq*16 + (fq*4+r)
    float linv[4];
    #pragma unroll
    for (int r = 0; r < 4; r++)
        linv[r] = 1.0f / __shfl(l_s, (lane & 48) + fq * 4 + r);
    #pragma unroll
    for (int n0 = 0; n0 < 8; n0++)
        #pragma unroll
        for (int r = 0; r < 4; r++) {
            int t = tw + fq * 4 + r;
            O[(size_t)t * 2048 + h * 128 + n0 * 16 + fr] =
                f2bf(Oacc[n0][r] * linv[r]);
        }
}

// ---------------------------------------------------------------------------
// Launcher (memory map at top of file). 5 launches (was 7).
// ---------------------------------------------------------------------------
extern "C" void kernel_launch(void* const* d_in, const int* in_sizes, int n_in,
                              void* d_out, int out_size, void* d_ws, size_t ws_size,
                              hipStream_t stream)
{
    const float* x  = (const float*)d_in[0];
    const float* Wq = (const float*)d_in[1];
    const float* bq = (const float*)d_in[2];
    const float* Wk = (const float*)d_in[3];
    const float* bk = (const float*)d_in[4];
    const float* Wv = (const float*)d_in[5];
    const float* bv = (const float*)d_in[6];
    const float* Wo = (const float*)d_in[7];
    const float* bo = (const float*)d_in[8];
    float* out = (float*)d_out;

    if (ws_size < 33554432) return;

    char* ws = (char*)d_ws;
    s16* xb    = (s16*)(ws + 0);           // [4096][2048] bf16 (16 MB)
    s16* At    = (s16*)(ws + 0);           // [2][2048][2048] bf16 (after xb dies)
    s16* Wqkvt = (s16*)(ws + 16777216);    // [3072][2048] bf16 (12 MB)
    s16* Wot   = (s16*)(ws + 16777216);    // [2048][2048] bf16 (after QKV GEMM)
    float2* tab = (float2*)(ws + 29360128); // [2048][64] cos/sin (1 MB, 28M+1M<=32M)
    s16* Qb    = (s16*)d_out;                              // [4096][2048] bf16
    s16* Kb    = (s16*)((char*)d_out + 16777216);          // [4096][512]  bf16
    s16* Vt    = (s16*)((char*)d_out + 20971520);          // [512][4096]  bf16

    // fused: x cast + QKV weight transpose + RoPE table
    prep<<<dim3(64, 64, 5), 256, 0, stream>>>(Wq, Wk, Wv, x, Wqkvt, tab, xb);

    // fused QKV projection + RoPE epilogue
    gemm_bk64<0><<<dim3(32, 24), 256, 0, stream>>>(xb, Wqkvt, bq, bk, bv, tab,
                                                   Qb, Kb, Vt, 4096, 3072, 2048);

    // O weight (overwrites Wqkvt; stream-ordered after QKV GEMM)
    castT<<<dim3(64, 64), 256, 0, stream>>>(Wo, Wot);

    // attention, both batches (xb dead -> At reuses its space)
    attn_kernel<<<dim3(32, 16, 2), 256, 0, stream>>>(Qb, Kb, Vt, At);

    // output projection: At [4096][2048] x Wot + bo -> out fp32
    gemm_bk64<2><<<dim3(32, 16), 256, 0, stream>>>(At, Wot, bo, nullptr, nullptr,
                                                   nullptr, out, nullptr, nullptr,
                                                   4096, 2048, 2048);
}